// Round 4
// baseline (533.658 us; speedup 1.0000x reference)
//
#include <hip/hip_runtime.h>
#include <cmath>

#pragma clang fp contract(off)

// Faithful f32 emulation of numpy's np.linalg.svd (LAPACK sgesdd, jobz='S')
// for the 8x4 triangulation matrices, since the harness reference is the f32
// LAPACK pipeline and its rounding noise is amplified ~1e6x at near-degenerate
// instances (rounds 1-3 evidence). Path for m=8,n=4 (m>=mnthr=7):
// sgeqr2 -> R -> sgebd2 -> sbdsqr (via sbdsdc/slasdq) -> sormbr('P','R','T').

constexpr int BATCH  = 65536;
constexpr int VIEWS  = 4;
constexpr int JOINTS = 17;
constexpr int TOTAL  = BATCH * JOINTS;   // 1,114,112 = 4352 * 256

#define EPS32  5.9604645e-08f   /* slamch('E') = 2^-24 */
#define UNFL32 1.17549435e-38f  /* slamch('S') */

__device__ __forceinline__ float fsign(float a, float b) { return copysignf(a, b); }

// snrm2: OpenBLAS x86-64 style — plain double accumulation, one rounding.
__device__ float snrm2_(const float* x, int n) {
    double s = 0.0;
    for (int i = 0; i < n; ++i) { double xi = (double)x[i]; s += xi * xi; }
    return (float)sqrt(s);
}

__device__ float slapy2_(float x, float y) {
    float xa = fabsf(x), ya = fabsf(y);
    float w = fmaxf(xa, ya), z = fminf(xa, ya);
    if (z == 0.0f) return w;
    float q = z / w;
    return w * __fsqrt_rn(1.0f + q * q);
}

// slarfg: returns tau; alpha in/out; x[0..n-2] in/out.
__device__ float slarfg_(int n, float& alpha, float* x) {
    if (n <= 1) return 0.0f;
    float xnorm = snrm2_(x, n - 1);
    if (xnorm == 0.0f) return 0.0f;
    float beta = -fsign(slapy2_(alpha, xnorm), alpha);
    float tau  = (beta - alpha) / beta;
    float scal = 1.0f / (alpha - beta);
    for (int i = 0; i < n - 1; ++i) x[i] = scal * x[i];
    alpha = beta;
    return tau;
}

// LAPACK >=3.10 slartg (common well-scaled branch).
__device__ void slartg_(float f, float g, float& c, float& s, float& r) {
    if (g == 0.0f)      { c = 1.0f; s = 0.0f; r = f; }
    else if (f == 0.0f) { c = 0.0f; s = fsign(1.0f, g); r = fabsf(g); }
    else {
        float f1 = fabsf(f);
        float dd = __fsqrt_rn(f * f + g * g);
        c = f1 / dd;
        r = fsign(dd, f);
        s = g / r;
    }
}

__device__ void slas2_(float f, float g, float h, float& ssmin, float& ssmax) {
    float fa = fabsf(f), ga = fabsf(g), ha = fabsf(h);
    float fhmn = fminf(fa, ha), fhmx = fmaxf(fa, ha);
    if (fhmn == 0.0f) {
        ssmin = 0.0f;
        if (fhmx == 0.0f) ssmax = ga;
        else {
            float mn = fminf(fhmx, ga), mx = fmaxf(fhmx, ga);
            float q = mn / mx;
            ssmax = mx * __fsqrt_rn(1.0f + q * q);
        }
    } else {
        if (ga < fhmx) {
            float as_ = 1.0f + fhmn / fhmx;
            float at_ = (fhmx - fhmn) / fhmx;
            float q = ga / fhmx;
            float au = q * q;
            float cc = 2.0f / (__fsqrt_rn(as_ * as_ + au) + __fsqrt_rn(at_ * at_ + au));
            ssmin = fhmn * cc;
            ssmax = fhmx / cc;
        } else {
            float au = fhmx / ga;
            if (au == 0.0f) { ssmin = (fhmn * fhmx) / ga; ssmax = ga; }
            else {
                float as_ = 1.0f + fhmn / fhmx;
                float at_ = (fhmx - fhmn) / fhmx;
                float t1 = as_ * au, t2 = at_ * au;
                float cc = 1.0f / (__fsqrt_rn(1.0f + t1 * t1) + __fsqrt_rn(1.0f + t2 * t2));
                ssmin = (fhmn * cc) * au;
                ssmin = ssmin + ssmin;
                ssmax = ga / (cc + cc);
            }
        }
    }
}

__device__ void slasv2_(float f, float g, float h,
                        float& ssmin, float& ssmax,
                        float& snr, float& csr, float& snl, float& csl) {
    float ft = f, fa = fabsf(f), ht = h, ha = fabsf(h);
    int pmax = 1;
    bool swap = (ha > fa);
    if (swap) { pmax = 3; float t = ft; ft = ht; ht = t; t = fa; fa = ha; ha = t; }
    float gt = g, ga = fabsf(g);
    float clt = 0.0f, crt = 0.0f, slt = 0.0f, srt = 0.0f;
    if (ga == 0.0f) {
        ssmin = ha; ssmax = fa;
        clt = 1.0f; crt = 1.0f; slt = 0.0f; srt = 0.0f;
    } else {
        bool gasmal = true;
        if (ga > fa) {
            pmax = 2;
            if ((fa / ga) < EPS32) {
                gasmal = false;
                ssmax = ga;
                if (ha > 1.0f) ssmin = fa / (ga / ha);
                else           ssmin = (fa / ga) * ha;
                clt = 1.0f; slt = ht / gt;
                srt = 1.0f; crt = ft / gt;
            }
        }
        if (gasmal) {
            float dd = fa - ha;
            float l_ = (dd == fa) ? 1.0f : (dd / fa);
            float m_ = gt / ft;
            float t_ = 2.0f - l_;
            float mm = m_ * m_, tt = t_ * t_;
            float s_ = __fsqrt_rn(tt + mm);
            float r_ = (l_ == 0.0f) ? fabsf(m_) : __fsqrt_rn(l_ * l_ + mm);
            float a_ = 0.5f * (s_ + r_);
            ssmin = ha / a_;
            ssmax = fa * a_;
            if (mm == 0.0f) {
                if (l_ == 0.0f) t_ = fsign(2.0f, ft) * fsign(1.0f, gt);
                else            t_ = gt / fsign(dd, ft) + m_ / t_;
            } else {
                t_ = (m_ / (s_ + t_) + m_ / (r_ + l_)) * (1.0f + a_);
            }
            float ll = __fsqrt_rn(t_ * t_ + 4.0f);
            crt = 2.0f / ll;
            srt = t_ / ll;
            clt = (crt + srt * m_) / a_;
            slt = (ht / ft) * srt / a_;
        }
    }
    if (swap) { csl = srt; snl = crt; csr = slt; snr = clt; }
    else      { csl = clt; snl = slt; csr = crt; snr = srt; }
    float tsign = 0.0f;
    if (pmax == 1) tsign = fsign(1.0f, csr) * fsign(1.0f, csl) * fsign(1.0f, f);
    if (pmax == 2) tsign = fsign(1.0f, snr) * fsign(1.0f, csl) * fsign(1.0f, g);
    if (pmax == 3) tsign = fsign(1.0f, snr) * fsign(1.0f, snl) * fsign(1.0f, h);
    ssmax = fsign(ssmax, tsign);
    ssmin = fsign(ssmin, tsign * fsign(1.0f, f) * fsign(1.0f, h));
}

// sbdsqr for n=4, uplo='U', ncvt=4, nru=0 — faithful reference translation.
__device__ void sbdsqr4_(float* d, float* e, float VT[4][4]) {
    const float eps = EPS32, unfl = UNFL32;
    const float tol = 10.0f * eps;              // tolmul = max(10,min(100,eps^-1/8)=8) = 10
    float thresh;
    {
        float sminoa = fabsf(d[0]);
        if (sminoa != 0.0f) {
            float mu = sminoa;
            for (int i = 1; i < 4; ++i) {
                mu = fabsf(d[i]) * (mu / (mu + fabsf(e[i - 1])));
                sminoa = fminf(sminoa, mu);
                if (sminoa == 0.0f) break;
            }
        }
        sminoa = sminoa / __fsqrt_rn(4.0f);
        thresh = fmaxf(tol * sminoa, 6.0f * (4.0f * (4.0f * unfl)));
    }
    int M = 4, oldll = -1000, oldm = -1000, idir = 0;
    float sminl = 0.0f;
    float rc[3], rs[3];
    for (int guard = 0; guard < 300 && M > 1; ++guard) {
        // ---- find block [LL..M] ----
        float smaxb = fabsf(d[M - 1]);
        int LLs = 0; bool defl = false, split = false;
        for (int lll = 1; lll <= M - 1; ++lll) {
            int ll = M - lll;
            float abse = fabsf(e[ll - 1]);
            float abss = fabsf(d[ll - 1]);
            if (abse <= thresh) {
                e[ll - 1] = 0.0f;
                if (ll == M - 1) { M = M - 1; defl = true; }
                else { LLs = ll; split = true; }
                break;
            }
            smaxb = fmaxf(fmaxf(smaxb, abss), abse);
        }
        if (defl) continue;
        int LL = (split ? LLs : 0) + 1;
        if (LL == M - 1) {
            // 2x2 block
            float sigmn, sigmx, sinr, cosr, sinl, cosl;
            slasv2_(d[M - 2], e[M - 2], d[M - 1], sigmn, sigmx, sinr, cosr, sinl, cosl);
            d[M - 2] = sigmx; e[M - 2] = 0.0f; d[M - 1] = sigmn;
            for (int cc = 0; cc < 4; ++cc) {     // srot(VT row M-2, row M-1, cosr, sinr)
                float st = cosr * VT[M - 2][cc] + sinr * VT[M - 1][cc];
                VT[M - 1][cc] = cosr * VT[M - 1][cc] - sinr * VT[M - 2][cc];
                VT[M - 2][cc] = st;
            }
            M -= 2;
            continue;
        }
        if (LL > oldm || M < oldll)
            idir = (fabsf(d[LL - 1]) >= fabsf(d[M - 1])) ? 1 : 2;
        bool cyc = false;
        if (idir == 1) {
            if (fabsf(e[M - 2]) <= tol * fabsf(d[M - 1])) { e[M - 2] = 0.0f; continue; }
            float mu = fabsf(d[LL - 1]); sminl = mu;
            for (int lll = LL; lll <= M - 1; ++lll) {
                if (fabsf(e[lll - 1]) <= tol * mu) { e[lll - 1] = 0.0f; cyc = true; break; }
                mu = fabsf(d[lll]) * (mu / (mu + fabsf(e[lll - 1])));
                sminl = fminf(sminl, mu);
            }
        } else {
            if (fabsf(e[LL - 1]) <= tol * fabsf(d[LL - 1])) { e[LL - 1] = 0.0f; continue; }
            float mu = fabsf(d[M - 1]); sminl = mu;
            for (int lll = M - 1; lll >= LL; --lll) {
                if (fabsf(e[lll - 1]) <= tol * mu) { e[lll - 1] = 0.0f; cyc = true; break; }
                mu = fabsf(d[lll - 1]) * (mu / (mu + fabsf(e[lll - 1])));
                sminl = fminf(sminl, mu);
            }
        }
        if (cyc) continue;
        oldll = LL; oldm = M;
        // ---- shift ----
        float shift = 0.0f;
        {
            float lhs = (4.0f * tol) * (sminl / smaxb);
            if (!(lhs <= fmaxf(eps, 0.01f * tol))) {
                float sll, rr2;
                if (idir == 1) { sll = fabsf(d[LL - 1]); slas2_(d[M - 2], e[M - 2], d[M - 1], shift, rr2); }
                else           { sll = fabsf(d[M - 1]); slas2_(d[LL - 1], e[LL - 1], d[LL], shift, rr2); }
                if (sll > 0.0f) {
                    float q = shift / sll;
                    if (q * q < eps) shift = 0.0f;
                }
            }
        }
        // ---- QR step ----
        if (shift == 0.0f) {
            if (idir == 1) {
                float cs = 1.0f, oldcs = 1.0f, sn = 0.0f, oldsn = 0.0f, rr = 0.0f;
                for (int i = LL; i <= M - 1; ++i) {
                    float fv = d[i - 1] * cs;
                    slartg_(fv, e[i - 1], cs, sn, rr);
                    if (i > LL) e[i - 2] = oldsn * rr;
                    float fv2 = oldcs * rr;
                    float gv2 = d[i] * sn;
                    slartg_(fv2, gv2, oldcs, oldsn, d[i - 1]);
                    rc[i - LL] = cs; rs[i - LL] = sn;
                }
                float h = d[M - 1] * cs;
                d[M - 1] = h * oldcs;
                e[M - 2] = h * oldsn;
                for (int jj = 0; jj < M - LL; ++jj) {           // slasr 'F'
                    float c = rc[jj], s = rs[jj];
                    if (c != 1.0f || s != 0.0f) {
                        int r0 = LL - 1 + jj;
                        for (int cc = 0; cc < 4; ++cc) {
                            float tmp = VT[r0 + 1][cc];
                            VT[r0 + 1][cc] = c * tmp - s * VT[r0][cc];
                            VT[r0][cc]     = s * tmp + c * VT[r0][cc];
                        }
                    }
                }
                if (fabsf(e[M - 2]) <= thresh) e[M - 2] = 0.0f;
            } else {
                float cs = 1.0f, oldcs = 1.0f, sn = 0.0f, oldsn = 0.0f, rr = 0.0f;
                for (int i = M; i >= LL + 1; --i) {
                    float fv = d[i - 1] * cs;
                    slartg_(fv, e[i - 2], cs, sn, rr);
                    if (i < M) e[i - 1] = oldsn * rr;
                    float fv2 = oldcs * rr;
                    float gv2 = d[i - 2] * sn;
                    slartg_(fv2, gv2, oldcs, oldsn, d[i - 1]);
                    rc[i - LL - 1] = oldcs; rs[i - LL - 1] = -oldsn;
                }
                float h = d[LL - 1] * cs;
                d[LL - 1] = h * oldcs;
                e[LL - 1] = h * oldsn;
                for (int jj = M - LL - 1; jj >= 0; --jj) {      // slasr 'B'
                    float c = rc[jj], s = rs[jj];
                    if (c != 1.0f || s != 0.0f) {
                        int r0 = LL - 1 + jj;
                        for (int cc = 0; cc < 4; ++cc) {
                            float tmp = VT[r0 + 1][cc];
                            VT[r0 + 1][cc] = c * tmp - s * VT[r0][cc];
                            VT[r0][cc]     = s * tmp + c * VT[r0][cc];
                        }
                    }
                }
                if (fabsf(e[LL - 1]) <= thresh) e[LL - 1] = 0.0f;
            }
        } else {
            if (idir == 1) {
                float fv = (fabsf(d[LL - 1]) - shift) * (fsign(1.0f, d[LL - 1]) + shift / d[LL - 1]);
                float gv = e[LL - 1];
                float cosr, sinr, cosl, sinl, rr;
                for (int i = LL; i <= M - 1; ++i) {
                    slartg_(fv, gv, cosr, sinr, rr);
                    if (i > LL) e[i - 2] = rr;
                    fv = cosr * d[i - 1] + sinr * e[i - 1];
                    e[i - 1] = cosr * e[i - 1] - sinr * d[i - 1];
                    gv = sinr * d[i];
                    d[i] = cosr * d[i];
                    slartg_(fv, gv, cosl, sinl, rr);
                    d[i - 1] = rr;
                    fv = cosl * e[i - 1] + sinl * d[i];
                    d[i] = cosl * d[i] - sinl * e[i - 1];
                    if (i < M - 1) { gv = sinl * e[i]; e[i] = cosl * e[i]; }
                    rc[i - LL] = cosr; rs[i - LL] = sinr;
                }
                e[M - 2] = fv;
                for (int jj = 0; jj < M - LL; ++jj) {           // slasr 'F'
                    float c = rc[jj], s = rs[jj];
                    if (c != 1.0f || s != 0.0f) {
                        int r0 = LL - 1 + jj;
                        for (int cc = 0; cc < 4; ++cc) {
                            float tmp = VT[r0 + 1][cc];
                            VT[r0 + 1][cc] = c * tmp - s * VT[r0][cc];
                            VT[r0][cc]     = s * tmp + c * VT[r0][cc];
                        }
                    }
                }
                if (fabsf(e[M - 2]) <= thresh) e[M - 2] = 0.0f;
            } else {
                float fv = (fabsf(d[M - 1]) - shift) * (fsign(1.0f, d[M - 1]) + shift / d[M - 1]);
                float gv = e[M - 2];
                float cosr, sinr, cosl, sinl, rr;
                for (int i = M; i >= LL + 1; --i) {
                    slartg_(fv, gv, cosr, sinr, rr);
                    if (i < M) e[i - 1] = rr;
                    fv = cosr * d[i - 1] + sinr * e[i - 2];
                    e[i - 2] = cosr * e[i - 2] - sinr * d[i - 1];
                    gv = sinr * d[i - 2];
                    d[i - 2] = cosr * d[i - 2];
                    slartg_(fv, gv, cosl, sinl, rr);
                    d[i - 1] = rr;
                    fv = cosl * e[i - 2] + sinl * d[i - 2];
                    d[i - 2] = cosl * d[i - 2] - sinl * e[i - 2];
                    if (i > LL + 1) { gv = sinl * e[i - 3]; e[i - 3] = cosl * e[i - 3]; }
                    rc[i - LL - 1] = cosl; rs[i - LL - 1] = -sinl;
                }
                e[LL - 1] = fv;
                if (fabsf(e[LL - 1]) <= thresh) e[LL - 1] = 0.0f;
                for (int jj = M - LL - 1; jj >= 0; --jj) {      // slasr 'B'
                    float c = rc[jj], s = rs[jj];
                    if (c != 1.0f || s != 0.0f) {
                        int r0 = LL - 1 + jj;
                        for (int cc = 0; cc < 4; ++cc) {
                            float tmp = VT[r0 + 1][cc];
                            VT[r0 + 1][cc] = c * tmp - s * VT[r0][cc];
                            VT[r0][cc]     = s * tmp + c * VT[r0][cc];
                        }
                    }
                }
            }
        }
    }
    // make singular values positive
    for (int i = 0; i < 4; ++i) {
        if (d[i] < 0.0f) {
            d[i] = -d[i];
            for (int cc = 0; cc < 4; ++cc) VT[i][cc] = -VT[i][cc];
        }
    }
    // sort decreasing (LAPACK selection + swap)
    for (int i = 1; i <= 3; ++i) {
        int isub = 0; float smn = d[0];
        for (int jj = 1; jj <= 4 - i; ++jj)
            if (d[jj] <= smn) { isub = jj; smn = d[jj]; }
        int tgt = 4 - i;
        if (isub != tgt) {
            d[isub] = d[tgt]; d[tgt] = smn;
            for (int cc = 0; cc < 4; ++cc) {
                float t = VT[isub][cc]; VT[isub][cc] = VT[tgt][cc]; VT[tgt][cc] = t;
            }
        }
    }
}

__global__ __launch_bounds__(256) void triangulate_kernel(
    const float* __restrict__ points,   // (B,V,J,2)
    const float* __restrict__ confs,    // (B,V,J)
    const float* __restrict__ proj,     // (B,V,3,4)
    float* __restrict__ out)            // (B,J,3)
{
    int tid = blockIdx.x * blockDim.x + threadIdx.x;
    if (tid >= TOTAL) return;
    int b = tid / JOINTS;
    int j = tid - b * JOINTS;

    // ---- Build A (8x4) in f32 with numpy's op order; column-major Acm[col][row]
    float Acm[4][8];
    #pragma unroll
    for (int v = 0; v < VIEWS; ++v) {
        int bv = b * VIEWS + v;
        const float4* Pq = (const float4*)(proj + (size_t)bv * 12);
        float4 P0 = Pq[0];
        float4 P1 = Pq[1];
        float4 P2 = Pq[2];
        float2 pt = *(const float2*)(points + ((size_t)bv * JOINTS + j) * 2);
        float  cf = confs[(size_t)bv * JOINTS + j];
        float p2[4] = {P2.x, P2.y, P2.z, P2.w};
        float p0[4] = {P0.x, P0.y, P0.z, P0.w};
        float p1[4] = {P1.x, P1.y, P1.z, P1.w};
        #pragma unroll
        for (int cc = 0; cc < 4; ++cc) {
            float r0 = (p2[cc] * pt.x) - p0[cc];
            float r1 = (p2[cc] * pt.y) - p1[cc];
            Acm[cc][2 * v + 0] = r0 * cf;
            Acm[cc][2 * v + 1] = r1 * cf;
        }
    }

    // ---- sgeqr2 (8x4): unblocked Householder QR ----
    for (int jc = 0; jc < 4; ++jc) {
        float alpha = Acm[jc][jc];
        float tau = slarfg_(8 - jc, alpha, &Acm[jc][jc + 1]);
        if (tau != 0.0f) {
            for (int c = jc + 1; c < 4; ++c) {
                float w = Acm[c][jc];                       // v0 = 1
                for (int r = jc + 1; r < 8; ++r) w = w + Acm[jc][r] * Acm[c][r];
                float temp = -tau * w;
                Acm[c][jc] = Acm[c][jc] + temp;
                for (int r = jc + 1; r < 8; ++r) Acm[c][r] = Acm[c][r] + Acm[jc][r] * temp;
            }
        }
        Acm[jc][jc] = alpha;
    }

    // ---- R (4x4 col-major), zero below diagonal ----
    float Rg[4][4];
    #pragma unroll
    for (int c = 0; c < 4; ++c)
        #pragma unroll
        for (int r = 0; r < 4; ++r)
            Rg[c][r] = (r <= c) ? Acm[c][r] : 0.0f;

    // ---- sgebd2 (4x4) -> bidiagonal d,e; right reflectors in rows of Rg ----
    float d_[4], e_[4], taup[4];
    for (int i = 0; i < 4; ++i) {
        float alpha = Rg[i][i];
        float tau = slarfg_(4 - i, alpha, &Rg[i][i + 1]);
        d_[i] = alpha;
        if (tau != 0.0f) {
            for (int c = i + 1; c < 4; ++c) {
                float w = Rg[c][i];
                for (int r = i + 1; r < 4; ++r) w = w + Rg[i][r] * Rg[c][r];
                float temp = -tau * w;
                Rg[c][i] = Rg[c][i] + temp;
                for (int r = i + 1; r < 4; ++r) Rg[c][r] = Rg[c][r] + Rg[i][r] * temp;
            }
        }
        if (i < 3) {
            float alpha2 = Rg[i + 1][i];
            float xb[2]; int nt = 2 - i;  // tail length of the row reflector
            for (int t = 0; t < nt && t < 2; ++t) xb[t] = Rg[i + 2 + t][i];
            float tau2 = slarfg_(3 - i, alpha2, xb);
            e_[i] = alpha2;
            for (int t = 0; t < nt && t < 2; ++t) Rg[i + 2 + t][i] = xb[t];
            taup[i] = tau2;
            if (tau2 != 0.0f) {
                for (int r = i + 1; r < 4; ++r) {
                    float w = Rg[i + 1][r];                  // v at col i+1 is 1
                    for (int c = i + 2; c < 4; ++c) w = w + Rg[c][i] * Rg[c][r];
                    float ntau = -tau2;
                    Rg[i + 1][r] = Rg[i + 1][r] + w * ntau;
                    for (int c = i + 2; c < 4; ++c) {
                        float tc = ntau * Rg[c][i];
                        Rg[c][r] = Rg[c][r] + w * tc;
                    }
                }
            }
        } else taup[i] = 0.0f;
    }

    // ---- sbdsqr on (d,e) with VT = I ----
    float VT[4][4] = {{1,0,0,0},{0,1,0,0},{0,0,1,0},{0,0,0,1}};
    sbdsqr4_(d_, e_, VT);

    // ---- sormbr('P','R','T'): VT := VT * G(k)...G(1), backward ----
    for (int ii = 2; ii >= 0; --ii) {
        float tau = taup[ii];
        if (tau == 0.0f) continue;
        for (int r = 0; r < 4; ++r) {
            float w = VT[r][ii + 1];                         // v = 1 at col ii+1
            for (int c = ii + 2; c < 4; ++c) w = w + VT[r][c] * Rg[c][ii];
            float ntau = -tau;
            VT[r][ii + 1] = VT[r][ii + 1] + w * ntau;
            for (int c = ii + 2; c < 4; ++c) {
                float tc = ntau * Rg[c][ii];
                VT[r][c] = VT[r][c] + w * tc;
            }
        }
    }

    // ---- output: vh[3][:3]/vh[3][3] in f32 (negations cancel bitwise) ----
    float w3 = VT[3][3];
    float* o = out + (size_t)tid * 3;
    o[0] = VT[3][0] / w3;
    o[1] = VT[3][1] / w3;
    o[2] = VT[3][2] / w3;
}

extern "C" void kernel_launch(void* const* d_in, const int* in_sizes, int n_in,
                              void* d_out, int out_size, void* d_ws, size_t ws_size,
                              hipStream_t stream) {
    const float* points = (const float*)d_in[0];
    const float* confs  = (const float*)d_in[1];
    const float* proj   = (const float*)d_in[2];
    float* out = (float*)d_out;

    dim3 block(256);
    dim3 grid((TOTAL + 255) / 256);   // 4352
    triangulate_kernel<<<grid, block, 0, stream>>>(points, confs, proj, out);
}

// Round 5
// 212.431 us; speedup vs baseline: 2.5121x; 2.5121x over previous
//
#include <hip/hip_runtime.h>
#include <cmath>

#pragma clang fp contract(off)

// Hybrid: cheap f32 one-sided Jacobi SVD for all instances + error estimate;
// only instances where the reference's own f32 noise amplification could
// exceed ~threshold/380 re-run the faithful sgesdd-f32 emulation (bit-identical
// to round 4, which passed with absmax 1.2e4 vs threshold 1.9e4).
// Error model (validated r1-r4): |exact - ref| ~ eps32 * s1/(s3-s4) * (1+|out|^2).

constexpr int BATCH  = 65536;
constexpr int VIEWS  = 4;
constexpr int JOINTS = 17;
constexpr int TOTAL  = BATCH * JOINTS;   // 1,114,112 = 4352 * 256

#define EPS32  5.9604645e-08f   /* slamch('E') = 2^-24 */
#define UNFL32 1.17549435e-38f  /* slamch('S') */

__device__ __forceinline__ float fsign(float a, float b) { return copysignf(a, b); }

// snrm2: OpenBLAS x86-64 style — plain double accumulation, one rounding.
__device__ float snrm2_(const float* x, int n) {
    double s = 0.0;
    for (int i = 0; i < n; ++i) { double xi = (double)x[i]; s += xi * xi; }
    return (float)sqrt(s);
}

__device__ float slapy2_(float x, float y) {
    float xa = fabsf(x), ya = fabsf(y);
    float w = fmaxf(xa, ya), z = fminf(xa, ya);
    if (z == 0.0f) return w;
    float q = z / w;
    return w * __fsqrt_rn(1.0f + q * q);
}

__device__ float slarfg_(int n, float& alpha, float* x) {
    if (n <= 1) return 0.0f;
    float xnorm = snrm2_(x, n - 1);
    if (xnorm == 0.0f) return 0.0f;
    float beta = -fsign(slapy2_(alpha, xnorm), alpha);
    float tau  = (beta - alpha) / beta;
    float scal = 1.0f / (alpha - beta);
    for (int i = 0; i < n - 1; ++i) x[i] = scal * x[i];
    alpha = beta;
    return tau;
}

__device__ void slartg_(float f, float g, float& c, float& s, float& r) {
    if (g == 0.0f)      { c = 1.0f; s = 0.0f; r = f; }
    else if (f == 0.0f) { c = 0.0f; s = fsign(1.0f, g); r = fabsf(g); }
    else {
        float f1 = fabsf(f);
        float dd = __fsqrt_rn(f * f + g * g);
        c = f1 / dd;
        r = fsign(dd, f);
        s = g / r;
    }
}

__device__ void slas2_(float f, float g, float h, float& ssmin, float& ssmax) {
    float fa = fabsf(f), ga = fabsf(g), ha = fabsf(h);
    float fhmn = fminf(fa, ha), fhmx = fmaxf(fa, ha);
    if (fhmn == 0.0f) {
        ssmin = 0.0f;
        if (fhmx == 0.0f) ssmax = ga;
        else {
            float mn = fminf(fhmx, ga), mx = fmaxf(fhmx, ga);
            float q = mn / mx;
            ssmax = mx * __fsqrt_rn(1.0f + q * q);
        }
    } else {
        if (ga < fhmx) {
            float as_ = 1.0f + fhmn / fhmx;
            float at_ = (fhmx - fhmn) / fhmx;
            float q = ga / fhmx;
            float au = q * q;
            float cc = 2.0f / (__fsqrt_rn(as_ * as_ + au) + __fsqrt_rn(at_ * at_ + au));
            ssmin = fhmn * cc;
            ssmax = fhmx / cc;
        } else {
            float au = fhmx / ga;
            if (au == 0.0f) { ssmin = (fhmn * fhmx) / ga; ssmax = ga; }
            else {
                float as_ = 1.0f + fhmn / fhmx;
                float at_ = (fhmx - fhmn) / fhmx;
                float t1 = as_ * au, t2 = at_ * au;
                float cc = 1.0f / (__fsqrt_rn(1.0f + t1 * t1) + __fsqrt_rn(1.0f + t2 * t2));
                ssmin = (fhmn * cc) * au;
                ssmin = ssmin + ssmin;
                ssmax = ga / (cc + cc);
            }
        }
    }
}

__device__ void slasv2_(float f, float g, float h,
                        float& ssmin, float& ssmax,
                        float& snr, float& csr, float& snl, float& csl) {
    float ft = f, fa = fabsf(f), ht = h, ha = fabsf(h);
    int pmax = 1;
    bool swap = (ha > fa);
    if (swap) { pmax = 3; float t = ft; ft = ht; ht = t; t = fa; fa = ha; ha = t; }
    float gt = g, ga = fabsf(g);
    float clt = 0.0f, crt = 0.0f, slt = 0.0f, srt = 0.0f;
    if (ga == 0.0f) {
        ssmin = ha; ssmax = fa;
        clt = 1.0f; crt = 1.0f; slt = 0.0f; srt = 0.0f;
    } else {
        bool gasmal = true;
        if (ga > fa) {
            pmax = 2;
            if ((fa / ga) < EPS32) {
                gasmal = false;
                ssmax = ga;
                if (ha > 1.0f) ssmin = fa / (ga / ha);
                else           ssmin = (fa / ga) * ha;
                clt = 1.0f; slt = ht / gt;
                srt = 1.0f; crt = ft / gt;
            }
        }
        if (gasmal) {
            float dd = fa - ha;
            float l_ = (dd == fa) ? 1.0f : (dd / fa);
            float m_ = gt / ft;
            float t_ = 2.0f - l_;
            float mm = m_ * m_, tt = t_ * t_;
            float s_ = __fsqrt_rn(tt + mm);
            float r_ = (l_ == 0.0f) ? fabsf(m_) : __fsqrt_rn(l_ * l_ + mm);
            float a_ = 0.5f * (s_ + r_);
            ssmin = ha / a_;
            ssmax = fa * a_;
            if (mm == 0.0f) {
                if (l_ == 0.0f) t_ = fsign(2.0f, ft) * fsign(1.0f, gt);
                else            t_ = gt / fsign(dd, ft) + m_ / t_;
            } else {
                t_ = (m_ / (s_ + t_) + m_ / (r_ + l_)) * (1.0f + a_);
            }
            float ll = __fsqrt_rn(t_ * t_ + 4.0f);
            crt = 2.0f / ll;
            srt = t_ / ll;
            clt = (crt + srt * m_) / a_;
            slt = (ht / ft) * srt / a_;
        }
    }
    if (swap) { csl = srt; snl = crt; csr = slt; snr = clt; }
    else      { csl = clt; snl = slt; csr = crt; snr = srt; }
    float tsign = 0.0f;
    if (pmax == 1) tsign = fsign(1.0f, csr) * fsign(1.0f, csl) * fsign(1.0f, f);
    if (pmax == 2) tsign = fsign(1.0f, snr) * fsign(1.0f, csl) * fsign(1.0f, g);
    if (pmax == 3) tsign = fsign(1.0f, snr) * fsign(1.0f, snl) * fsign(1.0f, h);
    ssmax = fsign(ssmax, tsign);
    ssmin = fsign(ssmin, tsign * fsign(1.0f, f) * fsign(1.0f, h));
}

// sbdsqr for n=4, uplo='U', ncvt=4, nru=0 — faithful reference translation.
__device__ void sbdsqr4_(float* d, float* e, float VT[4][4]) {
    const float eps = EPS32, unfl = UNFL32;
    const float tol = 10.0f * eps;
    float thresh;
    {
        float sminoa = fabsf(d[0]);
        if (sminoa != 0.0f) {
            float mu = sminoa;
            for (int i = 1; i < 4; ++i) {
                mu = fabsf(d[i]) * (mu / (mu + fabsf(e[i - 1])));
                sminoa = fminf(sminoa, mu);
                if (sminoa == 0.0f) break;
            }
        }
        sminoa = sminoa / __fsqrt_rn(4.0f);
        thresh = fmaxf(tol * sminoa, 6.0f * (4.0f * (4.0f * unfl)));
    }
    int M = 4, oldll = -1000, oldm = -1000, idir = 0;
    float sminl = 0.0f;
    float rc[3], rs[3];
    for (int guard = 0; guard < 300 && M > 1; ++guard) {
        float smaxb = fabsf(d[M - 1]);
        int LLs = 0; bool defl = false, split = false;
        for (int lll = 1; lll <= M - 1; ++lll) {
            int ll = M - lll;
            float abse = fabsf(e[ll - 1]);
            float abss = fabsf(d[ll - 1]);
            if (abse <= thresh) {
                e[ll - 1] = 0.0f;
                if (ll == M - 1) { M = M - 1; defl = true; }
                else { LLs = ll; split = true; }
                break;
            }
            smaxb = fmaxf(fmaxf(smaxb, abss), abse);
        }
        if (defl) continue;
        int LL = (split ? LLs : 0) + 1;
        if (LL == M - 1) {
            float sigmn, sigmx, sinr, cosr, sinl, cosl;
            slasv2_(d[M - 2], e[M - 2], d[M - 1], sigmn, sigmx, sinr, cosr, sinl, cosl);
            d[M - 2] = sigmx; e[M - 2] = 0.0f; d[M - 1] = sigmn;
            for (int cc = 0; cc < 4; ++cc) {
                float st = cosr * VT[M - 2][cc] + sinr * VT[M - 1][cc];
                VT[M - 1][cc] = cosr * VT[M - 1][cc] - sinr * VT[M - 2][cc];
                VT[M - 2][cc] = st;
            }
            M -= 2;
            continue;
        }
        if (LL > oldm || M < oldll)
            idir = (fabsf(d[LL - 1]) >= fabsf(d[M - 1])) ? 1 : 2;
        bool cyc = false;
        if (idir == 1) {
            if (fabsf(e[M - 2]) <= tol * fabsf(d[M - 1])) { e[M - 2] = 0.0f; continue; }
            float mu = fabsf(d[LL - 1]); sminl = mu;
            for (int lll = LL; lll <= M - 1; ++lll) {
                if (fabsf(e[lll - 1]) <= tol * mu) { e[lll - 1] = 0.0f; cyc = true; break; }
                mu = fabsf(d[lll]) * (mu / (mu + fabsf(e[lll - 1])));
                sminl = fminf(sminl, mu);
            }
        } else {
            if (fabsf(e[LL - 1]) <= tol * fabsf(d[LL - 1])) { e[LL - 1] = 0.0f; continue; }
            float mu = fabsf(d[M - 1]); sminl = mu;
            for (int lll = M - 1; lll >= LL; --lll) {
                if (fabsf(e[lll - 1]) <= tol * mu) { e[lll - 1] = 0.0f; cyc = true; break; }
                mu = fabsf(d[lll - 1]) * (mu / (mu + fabsf(e[lll - 1])));
                sminl = fminf(sminl, mu);
            }
        }
        if (cyc) continue;
        oldll = LL; oldm = M;
        float shift = 0.0f;
        {
            float lhs = (4.0f * tol) * (sminl / smaxb);
            if (!(lhs <= fmaxf(eps, 0.01f * tol))) {
                float sll, rr2;
                if (idir == 1) { sll = fabsf(d[LL - 1]); slas2_(d[M - 2], e[M - 2], d[M - 1], shift, rr2); }
                else           { sll = fabsf(d[M - 1]); slas2_(d[LL - 1], e[LL - 1], d[LL], shift, rr2); }
                if (sll > 0.0f) {
                    float q = shift / sll;
                    if (q * q < eps) shift = 0.0f;
                }
            }
        }
        if (shift == 0.0f) {
            if (idir == 1) {
                float cs = 1.0f, oldcs = 1.0f, sn = 0.0f, oldsn = 0.0f, rr = 0.0f;
                for (int i = LL; i <= M - 1; ++i) {
                    float fv = d[i - 1] * cs;
                    slartg_(fv, e[i - 1], cs, sn, rr);
                    if (i > LL) e[i - 2] = oldsn * rr;
                    float fv2 = oldcs * rr;
                    float gv2 = d[i] * sn;
                    slartg_(fv2, gv2, oldcs, oldsn, d[i - 1]);
                    rc[i - LL] = cs; rs[i - LL] = sn;
                }
                float h = d[M - 1] * cs;
                d[M - 1] = h * oldcs;
                e[M - 2] = h * oldsn;
                for (int jj = 0; jj < M - LL; ++jj) {
                    float c = rc[jj], s = rs[jj];
                    if (c != 1.0f || s != 0.0f) {
                        int r0 = LL - 1 + jj;
                        for (int cc = 0; cc < 4; ++cc) {
                            float tmp = VT[r0 + 1][cc];
                            VT[r0 + 1][cc] = c * tmp - s * VT[r0][cc];
                            VT[r0][cc]     = s * tmp + c * VT[r0][cc];
                        }
                    }
                }
                if (fabsf(e[M - 2]) <= thresh) e[M - 2] = 0.0f;
            } else {
                float cs = 1.0f, oldcs = 1.0f, sn = 0.0f, oldsn = 0.0f, rr = 0.0f;
                for (int i = M; i >= LL + 1; --i) {
                    float fv = d[i - 1] * cs;
                    slartg_(fv, e[i - 2], cs, sn, rr);
                    if (i < M) e[i - 1] = oldsn * rr;
                    float fv2 = oldcs * rr;
                    float gv2 = d[i - 2] * sn;
                    slartg_(fv2, gv2, oldcs, oldsn, d[i - 1]);
                    rc[i - LL - 1] = oldcs; rs[i - LL - 1] = -oldsn;
                }
                float h = d[LL - 1] * cs;
                d[LL - 1] = h * oldcs;
                e[LL - 1] = h * oldsn;
                for (int jj = M - LL - 1; jj >= 0; --jj) {
                    float c = rc[jj], s = rs[jj];
                    if (c != 1.0f || s != 0.0f) {
                        int r0 = LL - 1 + jj;
                        for (int cc = 0; cc < 4; ++cc) {
                            float tmp = VT[r0 + 1][cc];
                            VT[r0 + 1][cc] = c * tmp - s * VT[r0][cc];
                            VT[r0][cc]     = s * tmp + c * VT[r0][cc];
                        }
                    }
                }
                if (fabsf(e[LL - 1]) <= thresh) e[LL - 1] = 0.0f;
            }
        } else {
            if (idir == 1) {
                float fv = (fabsf(d[LL - 1]) - shift) * (fsign(1.0f, d[LL - 1]) + shift / d[LL - 1]);
                float gv = e[LL - 1];
                float cosr, sinr, cosl, sinl, rr;
                for (int i = LL; i <= M - 1; ++i) {
                    slartg_(fv, gv, cosr, sinr, rr);
                    if (i > LL) e[i - 2] = rr;
                    fv = cosr * d[i - 1] + sinr * e[i - 1];
                    e[i - 1] = cosr * e[i - 1] - sinr * d[i - 1];
                    gv = sinr * d[i];
                    d[i] = cosr * d[i];
                    slartg_(fv, gv, cosl, sinl, rr);
                    d[i - 1] = rr;
                    fv = cosl * e[i - 1] + sinl * d[i];
                    d[i] = cosl * d[i] - sinl * e[i - 1];
                    if (i < M - 1) { gv = sinl * e[i]; e[i] = cosl * e[i]; }
                    rc[i - LL] = cosr; rs[i - LL] = sinr;
                }
                e[M - 2] = fv;
                for (int jj = 0; jj < M - LL; ++jj) {
                    float c = rc[jj], s = rs[jj];
                    if (c != 1.0f || s != 0.0f) {
                        int r0 = LL - 1 + jj;
                        for (int cc = 0; cc < 4; ++cc) {
                            float tmp = VT[r0 + 1][cc];
                            VT[r0 + 1][cc] = c * tmp - s * VT[r0][cc];
                            VT[r0][cc]     = s * tmp + c * VT[r0][cc];
                        }
                    }
                }
                if (fabsf(e[M - 2]) <= thresh) e[M - 2] = 0.0f;
            } else {
                float fv = (fabsf(d[M - 1]) - shift) * (fsign(1.0f, d[M - 1]) + shift / d[M - 1]);
                float gv = e[M - 2];
                float cosr, sinr, cosl, sinl, rr;
                for (int i = M; i >= LL + 1; --i) {
                    slartg_(fv, gv, cosr, sinr, rr);
                    if (i < M) e[i - 1] = rr;
                    fv = cosr * d[i - 1] + sinr * e[i - 2];
                    e[i - 2] = cosr * e[i - 2] - sinr * d[i - 1];
                    gv = sinr * d[i - 2];
                    d[i - 2] = cosr * d[i - 2];
                    slartg_(fv, gv, cosl, sinl, rr);
                    d[i - 1] = rr;
                    fv = cosl * e[i - 2] + sinl * d[i - 2];
                    d[i - 2] = cosl * d[i - 2] - sinl * e[i - 2];
                    if (i > LL + 1) { gv = sinl * e[i - 3]; e[i - 3] = cosl * e[i - 3]; }
                    rc[i - LL - 1] = cosl; rs[i - LL - 1] = -sinl;
                }
                e[LL - 1] = fv;
                if (fabsf(e[LL - 1]) <= thresh) e[LL - 1] = 0.0f;
                for (int jj = M - LL - 1; jj >= 0; --jj) {
                    float c = rc[jj], s = rs[jj];
                    if (c != 1.0f || s != 0.0f) {
                        int r0 = LL - 1 + jj;
                        for (int cc = 0; cc < 4; ++cc) {
                            float tmp = VT[r0 + 1][cc];
                            VT[r0 + 1][cc] = c * tmp - s * VT[r0][cc];
                            VT[r0][cc]     = s * tmp + c * VT[r0][cc];
                        }
                    }
                }
            }
        }
    }
    for (int i = 0; i < 4; ++i) {
        if (d[i] < 0.0f) {
            d[i] = -d[i];
            for (int cc = 0; cc < 4; ++cc) VT[i][cc] = -VT[i][cc];
        }
    }
    for (int i = 1; i <= 3; ++i) {
        int isub = 0; float smn = d[0];
        for (int jj = 1; jj <= 4 - i; ++jj)
            if (d[jj] <= smn) { isub = jj; smn = d[jj]; }
        int tgt = 4 - i;
        if (isub != tgt) {
            d[isub] = d[tgt]; d[tgt] = smn;
            for (int cc = 0; cc < 4; ++cc) {
                float t = VT[isub][cc]; VT[isub][cc] = VT[tgt][cc]; VT[tgt][cc] = t;
            }
        }
    }
}

// Build A (8x4) in f32 with numpy's exact op order; column-major Acm[col][row].
__device__ __forceinline__ void build_A(const float* __restrict__ points,
                                        const float* __restrict__ confs,
                                        const float* __restrict__ proj,
                                        int b, int j, float Acm[4][8]) {
    #pragma unroll
    for (int v = 0; v < VIEWS; ++v) {
        int bv = b * VIEWS + v;
        const float4* Pq = (const float4*)(proj + (size_t)bv * 12);
        float4 P0 = Pq[0];
        float4 P1 = Pq[1];
        float4 P2 = Pq[2];
        float2 pt = *(const float2*)(points + ((size_t)bv * JOINTS + j) * 2);
        float  cf = confs[(size_t)bv * JOINTS + j];
        float p2[4] = {P2.x, P2.y, P2.z, P2.w};
        float p0[4] = {P0.x, P0.y, P0.z, P0.w};
        float p1[4] = {P1.x, P1.y, P1.z, P1.w};
        #pragma unroll
        for (int cc = 0; cc < 4; ++cc) {
            float r0 = (p2[cc] * pt.x) - p0[cc];
            float r1 = (p2[cc] * pt.y) - p1[cc];
            Acm[cc][2 * v + 0] = r0 * cf;
            Acm[cc][2 * v + 1] = r1 * cf;
        }
    }
}

__global__ __launch_bounds__(256) void triangulate_kernel(
    const float* __restrict__ points,   // (B,V,J,2)
    const float* __restrict__ confs,    // (B,V,J)
    const float* __restrict__ proj,     // (B,V,3,4)
    float* __restrict__ out)            // (B,J,3)
{
    int tid = blockIdx.x * blockDim.x + threadIdx.x;
    if (tid >= TOTAL) return;
    int b = tid / JOINTS;
    int j = tid - b * JOINTS;

    // ================= FAST PATH: f32 one-sided Jacobi =================
    float Acm[4][8];
    build_A(points, confs, proj, b, j, Acm);

    float V[4][4] = {{1,0,0,0},{0,1,0,0},{0,0,1,0},{0,0,0,1}};

    for (int sweep = 0; sweep < 8; ++sweep) {
        bool rot = false;
        #pragma unroll
        for (int p = 0; p < 3; ++p) {
            #pragma unroll
            for (int q = p + 1; q < 4; ++q) {
                float alpha = 0.0f, beta = 0.0f, gamma = 0.0f;
                #pragma unroll
                for (int i = 0; i < 8; ++i) {
                    float ap = Acm[p][i], aq = Acm[q][i];
                    alpha = fmaf(ap, ap, alpha);
                    beta  = fmaf(aq, aq, beta);
                    gamma = fmaf(ap, aq, gamma);
                }
                if (gamma * gamma > 1e-14f * (alpha * beta)) {
                    rot = true;
                    float zeta = 0.5f * (beta - alpha) / gamma;
                    float t  = copysignf(1.0f, zeta) /
                               (fabsf(zeta) + __fsqrt_rn(fmaf(zeta, zeta, 1.0f)));
                    float ci = __frsqrt_rn(fmaf(t, t, 1.0f));
                    float si = ci * t;
                    #pragma unroll
                    for (int i = 0; i < 8; ++i) {
                        float ap = Acm[p][i], aq = Acm[q][i];
                        Acm[p][i] = fmaf(ci, ap, -si * aq);
                        Acm[q][i] = fmaf(si, ap,  ci * aq);
                    }
                    #pragma unroll
                    for (int i = 0; i < 4; ++i) {
                        float vp = V[i][p], vq = V[i][q];
                        V[i][p] = fmaf(ci, vp, -si * vq);
                        V[i][q] = fmaf(si, vp,  ci * vq);
                    }
                }
            }
        }
        if (!__any((int)rot)) break;
    }

    // column norms^2 -> singular values
    float n[4];
    #pragma unroll
    for (int c = 0; c < 4; ++c) {
        float s = 0.0f;
        #pragma unroll
        for (int i = 0; i < 8; ++i) s = fmaf(Acm[c][i], Acm[c][i], s);
        n[c] = s;
    }
    int idx = 0; float nm = n[0];
    if (n[1] < nm) { nm = n[1]; idx = 1; }
    if (n[2] < nm) { nm = n[2]; idx = 2; }
    if (n[3] < nm) { nm = n[3]; idx = 3; }

    // sort singular values ascending (5-compare network)
    float s0 = __fsqrt_rn(n[0]), s1 = __fsqrt_rn(n[1]);
    float s2 = __fsqrt_rn(n[2]), s3 = __fsqrt_rn(n[3]);
    { float t;
      if (s0 > s1) { t = s0; s0 = s1; s1 = t; }
      if (s2 > s3) { t = s2; s2 = s3; s3 = t; }
      if (s0 > s2) { t = s0; s0 = s2; s2 = t; }
      if (s1 > s3) { t = s1; s1 = s3; s3 = t; }
      if (s1 > s2) { t = s1; s1 = s2; s2 = t; }
    }
    // ascending: s0 = sigma_min, s1 = second smallest, s3 = sigma_max
    float gap = s1 - s0;

    float hw  = V[3][idx];
    float inv = 1.0f / hw;
    float ox = V[0][idx] * inv;
    float oy = V[1][idx] * inv;
    float oz = V[2][idx] * inv;

    float osq = fmaf(ox, ox, fmaf(oy, oy, oz * oz));
    float est = EPS32 * (s3 / gap) * (1.0f + osq);
    // flag on large estimate, inf, or NaN (cutoff 50 => 380x margin vs 1.9e4)
    bool flag = !(est <= 50.0f);

    // ================= SLOW PATH: faithful sgesdd-f32 emulation =================
    if (flag) {
        build_A(points, confs, proj, b, j, Acm);   // rebuild (Jacobi destroyed it)

        // sgeqr2 (8x4)
        for (int jc = 0; jc < 4; ++jc) {
            float alpha = Acm[jc][jc];
            float tau = slarfg_(8 - jc, alpha, &Acm[jc][jc + 1]);
            if (tau != 0.0f) {
                for (int c = jc + 1; c < 4; ++c) {
                    float w = Acm[c][jc];
                    for (int r = jc + 1; r < 8; ++r) w = w + Acm[jc][r] * Acm[c][r];
                    float temp = -tau * w;
                    Acm[c][jc] = Acm[c][jc] + temp;
                    for (int r = jc + 1; r < 8; ++r) Acm[c][r] = Acm[c][r] + Acm[jc][r] * temp;
                }
            }
            Acm[jc][jc] = alpha;
        }

        float Rg[4][4];
        #pragma unroll
        for (int c = 0; c < 4; ++c)
            #pragma unroll
            for (int r = 0; r < 4; ++r)
                Rg[c][r] = (r <= c) ? Acm[c][r] : 0.0f;

        // sgebd2 (4x4)
        float d_[4], e_[4], taup[4];
        for (int i = 0; i < 4; ++i) {
            float alpha = Rg[i][i];
            float tau = slarfg_(4 - i, alpha, &Rg[i][i + 1]);
            d_[i] = alpha;
            if (tau != 0.0f) {
                for (int c = i + 1; c < 4; ++c) {
                    float w = Rg[c][i];
                    for (int r = i + 1; r < 4; ++r) w = w + Rg[i][r] * Rg[c][r];
                    float temp = -tau * w;
                    Rg[c][i] = Rg[c][i] + temp;
                    for (int r = i + 1; r < 4; ++r) Rg[c][r] = Rg[c][r] + Rg[i][r] * temp;
                }
            }
            if (i < 3) {
                float alpha2 = Rg[i + 1][i];
                float xb[2]; int nt = 2 - i;
                for (int t = 0; t < nt && t < 2; ++t) xb[t] = Rg[i + 2 + t][i];
                float tau2 = slarfg_(3 - i, alpha2, xb);
                e_[i] = alpha2;
                for (int t = 0; t < nt && t < 2; ++t) Rg[i + 2 + t][i] = xb[t];
                taup[i] = tau2;
                if (tau2 != 0.0f) {
                    for (int r = i + 1; r < 4; ++r) {
                        float w = Rg[i + 1][r];
                        for (int c = i + 2; c < 4; ++c) w = w + Rg[c][i] * Rg[c][r];
                        float ntau = -tau2;
                        Rg[i + 1][r] = Rg[i + 1][r] + w * ntau;
                        for (int c = i + 2; c < 4; ++c) {
                            float tc = ntau * Rg[c][i];
                            Rg[c][r] = Rg[c][r] + w * tc;
                        }
                    }
                }
            } else taup[i] = 0.0f;
        }

        float VT[4][4] = {{1,0,0,0},{0,1,0,0},{0,0,1,0},{0,0,0,1}};
        sbdsqr4_(d_, e_, VT);

        // sormbr('P','R','T') backward
        for (int ii = 2; ii >= 0; --ii) {
            float tau = taup[ii];
            if (tau == 0.0f) continue;
            for (int r = 0; r < 4; ++r) {
                float w = VT[r][ii + 1];
                for (int c = ii + 2; c < 4; ++c) w = w + VT[r][c] * Rg[c][ii];
                float ntau = -tau;
                VT[r][ii + 1] = VT[r][ii + 1] + w * ntau;
                for (int c = ii + 2; c < 4; ++c) {
                    float tc = ntau * Rg[c][ii];
                    VT[r][c] = VT[r][c] + w * tc;
                }
            }
        }

        float w3 = VT[3][3];
        ox = VT[3][0] / w3;
        oy = VT[3][1] / w3;
        oz = VT[3][2] / w3;
    }

    float* o = out + (size_t)tid * 3;
    o[0] = ox;
    o[1] = oy;
    o[2] = oz;
}

extern "C" void kernel_launch(void* const* d_in, const int* in_sizes, int n_in,
                              void* d_out, int out_size, void* d_ws, size_t ws_size,
                              hipStream_t stream) {
    const float* points = (const float*)d_in[0];
    const float* confs  = (const float*)d_in[1];
    const float* proj   = (const float*)d_in[2];
    float* out = (float*)d_out;

    dim3 block(256);
    dim3 grid((TOTAL + 255) / 256);   // 4352
    triangulate_kernel<<<grid, block, 0, stream>>>(points, confs, proj, out);
}

// Round 6
// 181.313 us; speedup vs baseline: 2.9433x; 1.1716x over previous
//
#include <hip/hip_runtime.h>
#include <cmath>

#pragma clang fp contract(off)

// Hybrid: cheap f32 one-sided Jacobi SVD (fast intrinsics, incremental norms)
// + error estimate; instances where the reference's own f32 noise could exceed
// ~threshold/380 re-run the faithful sgesdd-f32 emulation (bit-identical to
// round 4: passed, absmax 1.2e4 vs threshold 1.9e4).
// Error model (validated r1-r5): |exact - ref| ~ eps32 * s_max/gap * (1+|out|^2).

constexpr int BATCH  = 65536;
constexpr int VIEWS  = 4;
constexpr int JOINTS = 17;
constexpr int TOTAL  = BATCH * JOINTS;   // 1,114,112 = 4352 * 256

#define EPS32  5.9604645e-08f   /* slamch('E') = 2^-24 */
#define UNFL32 1.17549435e-38f  /* slamch('S') */

__device__ __forceinline__ float fsign(float a, float b) { return copysignf(a, b); }

// fast 1-ulp hardware ops (v_rcp_f32 / v_rsq_f32 / v_sqrt_f32) — fast path only
__device__ __forceinline__ float frcp(float x)  { return __builtin_amdgcn_rcpf(x); }
__device__ __forceinline__ float frsq(float x)  { return __builtin_amdgcn_rsqf(x); }
__device__ __forceinline__ float fsqrtf(float x){ return __builtin_amdgcn_sqrtf(x); }

// ===================== slow path (bit-identical to round 4) =====================

__device__ float snrm2_(const float* x, int n) {
    double s = 0.0;
    for (int i = 0; i < n; ++i) { double xi = (double)x[i]; s += xi * xi; }
    return (float)sqrt(s);
}

__device__ float slapy2_(float x, float y) {
    float xa = fabsf(x), ya = fabsf(y);
    float w = fmaxf(xa, ya), z = fminf(xa, ya);
    if (z == 0.0f) return w;
    float q = z / w;
    return w * __fsqrt_rn(1.0f + q * q);
}

__device__ float slarfg_(int n, float& alpha, float* x) {
    if (n <= 1) return 0.0f;
    float xnorm = snrm2_(x, n - 1);
    if (xnorm == 0.0f) return 0.0f;
    float beta = -fsign(slapy2_(alpha, xnorm), alpha);
    float tau  = (beta - alpha) / beta;
    float scal = 1.0f / (alpha - beta);
    for (int i = 0; i < n - 1; ++i) x[i] = scal * x[i];
    alpha = beta;
    return tau;
}

__device__ void slartg_(float f, float g, float& c, float& s, float& r) {
    if (g == 0.0f)      { c = 1.0f; s = 0.0f; r = f; }
    else if (f == 0.0f) { c = 0.0f; s = fsign(1.0f, g); r = fabsf(g); }
    else {
        float f1 = fabsf(f);
        float dd = __fsqrt_rn(f * f + g * g);
        c = f1 / dd;
        r = fsign(dd, f);
        s = g / r;
    }
}

__device__ void slas2_(float f, float g, float h, float& ssmin, float& ssmax) {
    float fa = fabsf(f), ga = fabsf(g), ha = fabsf(h);
    float fhmn = fminf(fa, ha), fhmx = fmaxf(fa, ha);
    if (fhmn == 0.0f) {
        ssmin = 0.0f;
        if (fhmx == 0.0f) ssmax = ga;
        else {
            float mn = fminf(fhmx, ga), mx = fmaxf(fhmx, ga);
            float q = mn / mx;
            ssmax = mx * __fsqrt_rn(1.0f + q * q);
        }
    } else {
        if (ga < fhmx) {
            float as_ = 1.0f + fhmn / fhmx;
            float at_ = (fhmx - fhmn) / fhmx;
            float q = ga / fhmx;
            float au = q * q;
            float cc = 2.0f / (__fsqrt_rn(as_ * as_ + au) + __fsqrt_rn(at_ * at_ + au));
            ssmin = fhmn * cc;
            ssmax = fhmx / cc;
        } else {
            float au = fhmx / ga;
            if (au == 0.0f) { ssmin = (fhmn * fhmx) / ga; ssmax = ga; }
            else {
                float as_ = 1.0f + fhmn / fhmx;
                float at_ = (fhmx - fhmn) / fhmx;
                float t1 = as_ * au, t2 = at_ * au;
                float cc = 1.0f / (__fsqrt_rn(1.0f + t1 * t1) + __fsqrt_rn(1.0f + t2 * t2));
                ssmin = (fhmn * cc) * au;
                ssmin = ssmin + ssmin;
                ssmax = ga / (cc + cc);
            }
        }
    }
}

__device__ void slasv2_(float f, float g, float h,
                        float& ssmin, float& ssmax,
                        float& snr, float& csr, float& snl, float& csl) {
    float ft = f, fa = fabsf(f), ht = h, ha = fabsf(h);
    int pmax = 1;
    bool swap = (ha > fa);
    if (swap) { pmax = 3; float t = ft; ft = ht; ht = t; t = fa; fa = ha; ha = t; }
    float gt = g, ga = fabsf(g);
    float clt = 0.0f, crt = 0.0f, slt = 0.0f, srt = 0.0f;
    if (ga == 0.0f) {
        ssmin = ha; ssmax = fa;
        clt = 1.0f; crt = 1.0f; slt = 0.0f; srt = 0.0f;
    } else {
        bool gasmal = true;
        if (ga > fa) {
            pmax = 2;
            if ((fa / ga) < EPS32) {
                gasmal = false;
                ssmax = ga;
                if (ha > 1.0f) ssmin = fa / (ga / ha);
                else           ssmin = (fa / ga) * ha;
                clt = 1.0f; slt = ht / gt;
                srt = 1.0f; crt = ft / gt;
            }
        }
        if (gasmal) {
            float dd = fa - ha;
            float l_ = (dd == fa) ? 1.0f : (dd / fa);
            float m_ = gt / ft;
            float t_ = 2.0f - l_;
            float mm = m_ * m_, tt = t_ * t_;
            float s_ = __fsqrt_rn(tt + mm);
            float r_ = (l_ == 0.0f) ? fabsf(m_) : __fsqrt_rn(l_ * l_ + mm);
            float a_ = 0.5f * (s_ + r_);
            ssmin = ha / a_;
            ssmax = fa * a_;
            if (mm == 0.0f) {
                if (l_ == 0.0f) t_ = fsign(2.0f, ft) * fsign(1.0f, gt);
                else            t_ = gt / fsign(dd, ft) + m_ / t_;
            } else {
                t_ = (m_ / (s_ + t_) + m_ / (r_ + l_)) * (1.0f + a_);
            }
            float ll = __fsqrt_rn(t_ * t_ + 4.0f);
            crt = 2.0f / ll;
            srt = t_ / ll;
            clt = (crt + srt * m_) / a_;
            slt = (ht / ft) * srt / a_;
        }
    }
    if (swap) { csl = srt; snl = crt; csr = slt; snr = clt; }
    else      { csl = clt; snl = slt; csr = crt; snr = srt; }
    float tsign = 0.0f;
    if (pmax == 1) tsign = fsign(1.0f, csr) * fsign(1.0f, csl) * fsign(1.0f, f);
    if (pmax == 2) tsign = fsign(1.0f, snr) * fsign(1.0f, csl) * fsign(1.0f, g);
    if (pmax == 3) tsign = fsign(1.0f, snr) * fsign(1.0f, snl) * fsign(1.0f, h);
    ssmax = fsign(ssmax, tsign);
    ssmin = fsign(ssmin, tsign * fsign(1.0f, f) * fsign(1.0f, h));
}

__device__ void sbdsqr4_(float* d, float* e, float VT[4][4]) {
    const float eps = EPS32, unfl = UNFL32;
    const float tol = 10.0f * eps;
    float thresh;
    {
        float sminoa = fabsf(d[0]);
        if (sminoa != 0.0f) {
            float mu = sminoa;
            for (int i = 1; i < 4; ++i) {
                mu = fabsf(d[i]) * (mu / (mu + fabsf(e[i - 1])));
                sminoa = fminf(sminoa, mu);
                if (sminoa == 0.0f) break;
            }
        }
        sminoa = sminoa / __fsqrt_rn(4.0f);
        thresh = fmaxf(tol * sminoa, 6.0f * (4.0f * (4.0f * unfl)));
    }
    int M = 4, oldll = -1000, oldm = -1000, idir = 0;
    float sminl = 0.0f;
    float rc[3], rs[3];
    for (int guard = 0; guard < 300 && M > 1; ++guard) {
        float smaxb = fabsf(d[M - 1]);
        int LLs = 0; bool defl = false, split = false;
        for (int lll = 1; lll <= M - 1; ++lll) {
            int ll = M - lll;
            float abse = fabsf(e[ll - 1]);
            float abss = fabsf(d[ll - 1]);
            if (abse <= thresh) {
                e[ll - 1] = 0.0f;
                if (ll == M - 1) { M = M - 1; defl = true; }
                else { LLs = ll; split = true; }
                break;
            }
            smaxb = fmaxf(fmaxf(smaxb, abss), abse);
        }
        if (defl) continue;
        int LL = (split ? LLs : 0) + 1;
        if (LL == M - 1) {
            float sigmn, sigmx, sinr, cosr, sinl, cosl;
            slasv2_(d[M - 2], e[M - 2], d[M - 1], sigmn, sigmx, sinr, cosr, sinl, cosl);
            d[M - 2] = sigmx; e[M - 2] = 0.0f; d[M - 1] = sigmn;
            for (int cc = 0; cc < 4; ++cc) {
                float st = cosr * VT[M - 2][cc] + sinr * VT[M - 1][cc];
                VT[M - 1][cc] = cosr * VT[M - 1][cc] - sinr * VT[M - 2][cc];
                VT[M - 2][cc] = st;
            }
            M -= 2;
            continue;
        }
        if (LL > oldm || M < oldll)
            idir = (fabsf(d[LL - 1]) >= fabsf(d[M - 1])) ? 1 : 2;
        bool cyc = false;
        if (idir == 1) {
            if (fabsf(e[M - 2]) <= tol * fabsf(d[M - 1])) { e[M - 2] = 0.0f; continue; }
            float mu = fabsf(d[LL - 1]); sminl = mu;
            for (int lll = LL; lll <= M - 1; ++lll) {
                if (fabsf(e[lll - 1]) <= tol * mu) { e[lll - 1] = 0.0f; cyc = true; break; }
                mu = fabsf(d[lll]) * (mu / (mu + fabsf(e[lll - 1])));
                sminl = fminf(sminl, mu);
            }
        } else {
            if (fabsf(e[LL - 1]) <= tol * fabsf(d[LL - 1])) { e[LL - 1] = 0.0f; continue; }
            float mu = fabsf(d[M - 1]); sminl = mu;
            for (int lll = M - 1; lll >= LL; --lll) {
                if (fabsf(e[lll - 1]) <= tol * mu) { e[lll - 1] = 0.0f; cyc = true; break; }
                mu = fabsf(d[lll - 1]) * (mu / (mu + fabsf(e[lll - 1])));
                sminl = fminf(sminl, mu);
            }
        }
        if (cyc) continue;
        oldll = LL; oldm = M;
        float shift = 0.0f;
        {
            float lhs = (4.0f * tol) * (sminl / smaxb);
            if (!(lhs <= fmaxf(eps, 0.01f * tol))) {
                float sll, rr2;
                if (idir == 1) { sll = fabsf(d[LL - 1]); slas2_(d[M - 2], e[M - 2], d[M - 1], shift, rr2); }
                else           { sll = fabsf(d[M - 1]); slas2_(d[LL - 1], e[LL - 1], d[LL], shift, rr2); }
                if (sll > 0.0f) {
                    float q = shift / sll;
                    if (q * q < eps) shift = 0.0f;
                }
            }
        }
        if (shift == 0.0f) {
            if (idir == 1) {
                float cs = 1.0f, oldcs = 1.0f, sn = 0.0f, oldsn = 0.0f, rr = 0.0f;
                for (int i = LL; i <= M - 1; ++i) {
                    float fv = d[i - 1] * cs;
                    slartg_(fv, e[i - 1], cs, sn, rr);
                    if (i > LL) e[i - 2] = oldsn * rr;
                    float fv2 = oldcs * rr;
                    float gv2 = d[i] * sn;
                    slartg_(fv2, gv2, oldcs, oldsn, d[i - 1]);
                    rc[i - LL] = cs; rs[i - LL] = sn;
                }
                float h = d[M - 1] * cs;
                d[M - 1] = h * oldcs;
                e[M - 2] = h * oldsn;
                for (int jj = 0; jj < M - LL; ++jj) {
                    float c = rc[jj], s = rs[jj];
                    if (c != 1.0f || s != 0.0f) {
                        int r0 = LL - 1 + jj;
                        for (int cc = 0; cc < 4; ++cc) {
                            float tmp = VT[r0 + 1][cc];
                            VT[r0 + 1][cc] = c * tmp - s * VT[r0][cc];
                            VT[r0][cc]     = s * tmp + c * VT[r0][cc];
                        }
                    }
                }
                if (fabsf(e[M - 2]) <= thresh) e[M - 2] = 0.0f;
            } else {
                float cs = 1.0f, oldcs = 1.0f, sn = 0.0f, oldsn = 0.0f, rr = 0.0f;
                for (int i = M; i >= LL + 1; --i) {
                    float fv = d[i - 1] * cs;
                    slartg_(fv, e[i - 2], cs, sn, rr);
                    if (i < M) e[i - 1] = oldsn * rr;
                    float fv2 = oldcs * rr;
                    float gv2 = d[i - 2] * sn;
                    slartg_(fv2, gv2, oldcs, oldsn, d[i - 1]);
                    rc[i - LL - 1] = oldcs; rs[i - LL - 1] = -oldsn;
                }
                float h = d[LL - 1] * cs;
                d[LL - 1] = h * oldcs;
                e[LL - 1] = h * oldsn;
                for (int jj = M - LL - 1; jj >= 0; --jj) {
                    float c = rc[jj], s = rs[jj];
                    if (c != 1.0f || s != 0.0f) {
                        int r0 = LL - 1 + jj;
                        for (int cc = 0; cc < 4; ++cc) {
                            float tmp = VT[r0 + 1][cc];
                            VT[r0 + 1][cc] = c * tmp - s * VT[r0][cc];
                            VT[r0][cc]     = s * tmp + c * VT[r0][cc];
                        }
                    }
                }
                if (fabsf(e[LL - 1]) <= thresh) e[LL - 1] = 0.0f;
            }
        } else {
            if (idir == 1) {
                float fv = (fabsf(d[LL - 1]) - shift) * (fsign(1.0f, d[LL - 1]) + shift / d[LL - 1]);
                float gv = e[LL - 1];
                float cosr, sinr, cosl, sinl, rr;
                for (int i = LL; i <= M - 1; ++i) {
                    slartg_(fv, gv, cosr, sinr, rr);
                    if (i > LL) e[i - 2] = rr;
                    fv = cosr * d[i - 1] + sinr * e[i - 1];
                    e[i - 1] = cosr * e[i - 1] - sinr * d[i - 1];
                    gv = sinr * d[i];
                    d[i] = cosr * d[i];
                    slartg_(fv, gv, cosl, sinl, rr);
                    d[i - 1] = rr;
                    fv = cosl * e[i - 1] + sinl * d[i];
                    d[i] = cosl * d[i] - sinl * e[i - 1];
                    if (i < M - 1) { gv = sinl * e[i]; e[i] = cosl * e[i]; }
                    rc[i - LL] = cosr; rs[i - LL] = sinr;
                }
                e[M - 2] = fv;
                for (int jj = 0; jj < M - LL; ++jj) {
                    float c = rc[jj], s = rs[jj];
                    if (c != 1.0f || s != 0.0f) {
                        int r0 = LL - 1 + jj;
                        for (int cc = 0; cc < 4; ++cc) {
                            float tmp = VT[r0 + 1][cc];
                            VT[r0 + 1][cc] = c * tmp - s * VT[r0][cc];
                            VT[r0][cc]     = s * tmp + c * VT[r0][cc];
                        }
                    }
                }
                if (fabsf(e[M - 2]) <= thresh) e[M - 2] = 0.0f;
            } else {
                float fv = (fabsf(d[M - 1]) - shift) * (fsign(1.0f, d[M - 1]) + shift / d[M - 1]);
                float gv = e[M - 2];
                float cosr, sinr, cosl, sinl, rr;
                for (int i = M; i >= LL + 1; --i) {
                    slartg_(fv, gv, cosr, sinr, rr);
                    if (i < M) e[i - 1] = rr;
                    fv = cosr * d[i - 1] + sinr * e[i - 2];
                    e[i - 2] = cosr * e[i - 2] - sinr * d[i - 1];
                    gv = sinr * d[i - 2];
                    d[i - 2] = cosr * d[i - 2];
                    slartg_(fv, gv, cosl, sinl, rr);
                    d[i - 1] = rr;
                    fv = cosl * e[i - 2] + sinl * d[i - 2];
                    d[i - 2] = cosl * d[i - 2] - sinl * e[i - 2];
                    if (i > LL + 1) { gv = sinl * e[i - 3]; e[i - 3] = cosl * e[i - 3]; }
                    rc[i - LL - 1] = cosl; rs[i - LL - 1] = -sinl;
                }
                e[LL - 1] = fv;
                if (fabsf(e[LL - 1]) <= thresh) e[LL - 1] = 0.0f;
                for (int jj = M - LL - 1; jj >= 0; --jj) {
                    float c = rc[jj], s = rs[jj];
                    if (c != 1.0f || s != 0.0f) {
                        int r0 = LL - 1 + jj;
                        for (int cc = 0; cc < 4; ++cc) {
                            float tmp = VT[r0 + 1][cc];
                            VT[r0 + 1][cc] = c * tmp - s * VT[r0][cc];
                            VT[r0][cc]     = s * tmp + c * VT[r0][cc];
                        }
                    }
                }
            }
        }
    }
    for (int i = 0; i < 4; ++i) {
        if (d[i] < 0.0f) {
            d[i] = -d[i];
            for (int cc = 0; cc < 4; ++cc) VT[i][cc] = -VT[i][cc];
        }
    }
    for (int i = 1; i <= 3; ++i) {
        int isub = 0; float smn = d[0];
        for (int jj = 1; jj <= 4 - i; ++jj)
            if (d[jj] <= smn) { isub = jj; smn = d[jj]; }
        int tgt = 4 - i;
        if (isub != tgt) {
            d[isub] = d[tgt]; d[tgt] = smn;
            for (int cc = 0; cc < 4; ++cc) {
                float t = VT[isub][cc]; VT[isub][cc] = VT[tgt][cc]; VT[tgt][cc] = t;
            }
        }
    }
}

// Build A (8x4) in f32 with numpy's exact op order; column-major Acm[col][row].
__device__ __forceinline__ void build_A(const float* __restrict__ points,
                                        const float* __restrict__ confs,
                                        const float* __restrict__ proj,
                                        int b, int j, float Acm[4][8]) {
    #pragma unroll
    for (int v = 0; v < VIEWS; ++v) {
        int bv = b * VIEWS + v;
        const float4* Pq = (const float4*)(proj + (size_t)bv * 12);
        float4 P0 = Pq[0];
        float4 P1 = Pq[1];
        float4 P2 = Pq[2];
        float2 pt = *(const float2*)(points + ((size_t)bv * JOINTS + j) * 2);
        float  cf = confs[(size_t)bv * JOINTS + j];
        float p2[4] = {P2.x, P2.y, P2.z, P2.w};
        float p0[4] = {P0.x, P0.y, P0.z, P0.w};
        float p1[4] = {P1.x, P1.y, P1.z, P1.w};
        #pragma unroll
        for (int cc = 0; cc < 4; ++cc) {
            float r0 = (p2[cc] * pt.x) - p0[cc];
            float r1 = (p2[cc] * pt.y) - p1[cc];
            Acm[cc][2 * v + 0] = r0 * cf;
            Acm[cc][2 * v + 1] = r1 * cf;
        }
    }
}

__global__ __launch_bounds__(256) void triangulate_kernel(
    const float* __restrict__ points,   // (B,V,J,2)
    const float* __restrict__ confs,    // (B,V,J)
    const float* __restrict__ proj,     // (B,V,3,4)
    float* __restrict__ out)            // (B,J,3)
{
    int tid = blockIdx.x * blockDim.x + threadIdx.x;
    if (tid >= TOTAL) return;
    int b = tid / JOINTS;
    int j = tid - b * JOINTS;

    // ================= FAST PATH: f32 one-sided Jacobi =================
    float Acm[4][8];
    build_A(points, confs, proj, b, j, Acm);

    float V[4][4] = {{1,0,0,0},{0,1,0,0},{0,0,1,0},{0,0,0,1}};

    // initial column norms (maintained incrementally across rotations)
    float nrm[4];
    #pragma unroll
    for (int c = 0; c < 4; ++c) {
        float s = 0.0f;
        #pragma unroll
        for (int i = 0; i < 8; ++i) s = fmaf(Acm[c][i], Acm[c][i], s);
        nrm[c] = s;
    }

    for (int sweep = 0; sweep < 6; ++sweep) {
        bool rot = false;
        #pragma unroll
        for (int p = 0; p < 3; ++p) {
            #pragma unroll
            for (int q = p + 1; q < 4; ++q) {
                float alpha = nrm[p], beta = nrm[q];
                float gamma = 0.0f;
                #pragma unroll
                for (int i = 0; i < 8; ++i)
                    gamma = fmaf(Acm[p][i], Acm[q][i], gamma);
                if (gamma * gamma > 1e-14f * (alpha * beta)) {
                    rot = true;
                    // zeta finite (gamma != 0); if |zeta|=inf => t=0 => identity
                    float zeta = 0.5f * (beta - alpha) * frcp(gamma);
                    float t  = fsign(frcp(fabsf(zeta) +
                                          fsqrtf(fmaf(zeta, zeta, 1.0f))), zeta);
                    float ci = frsq(fmaf(t, t, 1.0f));
                    float si = ci * t;
                    #pragma unroll
                    for (int i = 0; i < 8; ++i) {
                        float ap = Acm[p][i], aq = Acm[q][i];
                        Acm[p][i] = fmaf(ci, ap, -si * aq);
                        Acm[q][i] = fmaf(si, ap,  ci * aq);
                    }
                    #pragma unroll
                    for (int i = 0; i < 4; ++i) {
                        float vp = V[i][p], vq = V[i][q];
                        V[i][p] = fmaf(ci, vp, -si * vq);
                        V[i][q] = fmaf(si, vp,  ci * vq);
                    }
                    nrm[p] = fmaf(-t, gamma, alpha);
                    nrm[q] = fmaf( t, gamma, beta);
                }
            }
        }
        if (!__any((int)rot)) break;
    }

    // exact final column norms -> singular values
    float n[4];
    #pragma unroll
    for (int c = 0; c < 4; ++c) {
        float s = 0.0f;
        #pragma unroll
        for (int i = 0; i < 8; ++i) s = fmaf(Acm[c][i], Acm[c][i], s);
        n[c] = s;
    }
    int idx = 0; float nm = n[0];
    if (n[1] < nm) { nm = n[1]; idx = 1; }
    if (n[2] < nm) { nm = n[2]; idx = 2; }
    if (n[3] < nm) { nm = n[3]; idx = 3; }

    // sort singular values ascending (5-compare network)
    float s0 = fsqrtf(n[0]), s1 = fsqrtf(n[1]);
    float s2 = fsqrtf(n[2]), s3 = fsqrtf(n[3]);
    { float t;
      if (s0 > s1) { t = s0; s0 = s1; s1 = t; }
      if (s2 > s3) { t = s2; s2 = s3; s3 = t; }
      if (s0 > s2) { t = s0; s0 = s2; s2 = t; }
      if (s1 > s3) { t = s1; s1 = s3; s3 = t; }
      if (s1 > s2) { t = s1; s1 = s2; s2 = t; }
    }
    float gap = s1 - s0;   // gap==0 -> frcp(0)=inf -> est=inf -> flagged

    float hw  = V[3][idx];
    float inv = frcp(hw);
    float ox = V[0][idx] * inv;
    float oy = V[1][idx] * inv;
    float oz = V[2][idx] * inv;

    float osq = fmaf(ox, ox, fmaf(oy, oy, oz * oz));
    float est = EPS32 * (s3 * frcp(gap)) * (1.0f + osq);
    bool flag = !(est <= 50.0f);   // also catches NaN/inf

    // ================= SLOW PATH: faithful sgesdd-f32 emulation =================
    if (flag) {
        build_A(points, confs, proj, b, j, Acm);

        // sgeqr2 (8x4)
        for (int jc = 0; jc < 4; ++jc) {
            float alpha = Acm[jc][jc];
            float tau = slarfg_(8 - jc, alpha, &Acm[jc][jc + 1]);
            if (tau != 0.0f) {
                for (int c = jc + 1; c < 4; ++c) {
                    float w = Acm[c][jc];
                    for (int r = jc + 1; r < 8; ++r) w = w + Acm[jc][r] * Acm[c][r];
                    float temp = -tau * w;
                    Acm[c][jc] = Acm[c][jc] + temp;
                    for (int r = jc + 1; r < 8; ++r) Acm[c][r] = Acm[c][r] + Acm[jc][r] * temp;
                }
            }
            Acm[jc][jc] = alpha;
        }

        float Rg[4][4];
        #pragma unroll
        for (int c = 0; c < 4; ++c)
            #pragma unroll
            for (int r = 0; r < 4; ++r)
                Rg[c][r] = (r <= c) ? Acm[c][r] : 0.0f;

        // sgebd2 (4x4)
        float d_[4], e_[4], taup[4];
        for (int i = 0; i < 4; ++i) {
            float alpha = Rg[i][i];
            float tau = slarfg_(4 - i, alpha, &Rg[i][i + 1]);
            d_[i] = alpha;
            if (tau != 0.0f) {
                for (int c = i + 1; c < 4; ++c) {
                    float w = Rg[c][i];
                    for (int r = i + 1; r < 4; ++r) w = w + Rg[i][r] * Rg[c][r];
                    float temp = -tau * w;
                    Rg[c][i] = Rg[c][i] + temp;
                    for (int r = i + 1; r < 4; ++r) Rg[c][r] = Rg[c][r] + Rg[i][r] * temp;
                }
            }
            if (i < 3) {
                float alpha2 = Rg[i + 1][i];
                float xb[2]; int nt = 2 - i;
                for (int t = 0; t < nt && t < 2; ++t) xb[t] = Rg[i + 2 + t][i];
                float tau2 = slarfg_(3 - i, alpha2, xb);
                e_[i] = alpha2;
                for (int t = 0; t < nt && t < 2; ++t) Rg[i + 2 + t][i] = xb[t];
                taup[i] = tau2;
                if (tau2 != 0.0f) {
                    for (int r = i + 1; r < 4; ++r) {
                        float w = Rg[i + 1][r];
                        for (int c = i + 2; c < 4; ++c) w = w + Rg[c][i] * Rg[c][r];
                        float ntau = -tau2;
                        Rg[i + 1][r] = Rg[i + 1][r] + w * ntau;
                        for (int c = i + 2; c < 4; ++c) {
                            float tc = ntau * Rg[c][i];
                            Rg[c][r] = Rg[c][r] + w * tc;
                        }
                    }
                }
            } else taup[i] = 0.0f;
        }

        float VT[4][4] = {{1,0,0,0},{0,1,0,0},{0,0,1,0},{0,0,0,1}};
        sbdsqr4_(d_, e_, VT);

        // sormbr('P','R','T') backward
        for (int ii = 2; ii >= 0; --ii) {
            float tau = taup[ii];
            if (tau == 0.0f) continue;
            for (int r = 0; r < 4; ++r) {
                float w = VT[r][ii + 1];
                for (int c = ii + 2; c < 4; ++c) w = w + VT[r][c] * Rg[c][ii];
                float ntau = -tau;
                VT[r][ii + 1] = VT[r][ii + 1] + w * ntau;
                for (int c = ii + 2; c < 4; ++c) {
                    float tc = ntau * Rg[c][ii];
                    VT[r][c] = VT[r][c] + w * tc;
                }
            }
        }

        float w3 = VT[3][3];
        ox = VT[3][0] / w3;
        oy = VT[3][1] / w3;
        oz = VT[3][2] / w3;
    }

    float* o = out + (size_t)tid * 3;
    o[0] = ox;
    o[1] = oy;
    o[2] = oz;
}

extern "C" void kernel_launch(void* const* d_in, const int* in_sizes, int n_in,
                              void* d_out, int out_size, void* d_ws, size_t ws_size,
                              hipStream_t stream) {
    const float* points = (const float*)d_in[0];
    const float* confs  = (const float*)d_in[1];
    const float* proj   = (const float*)d_in[2];
    float* out = (float*)d_out;

    dim3 block(256);
    dim3 grid((TOTAL + 255) / 256);   // 4352
    triangulate_kernel<<<grid, block, 0, stream>>>(points, confs, proj, out);
}

// Round 7
// 168.841 us; speedup vs baseline: 3.1607x; 1.0739x over previous
//
#include <hip/hip_runtime.h>
#include <cmath>

#pragma clang fp contract(off)

// Hybrid: f32 one-sided Jacobi fast path + faithful sgesdd-f32 slow path.
// r6 counter arithmetic showed ~2k excess VALU ops/thread => slow-path wave
// hit rate was ~45% (lane flag rate ~1%, cutoff 50 too conservative).
// r7: cutoff 50 -> 1000 (model: |fast-ref| <~ 6*est; 6e3 << 1.9e4 threshold),
// 5 sweeps + final-sweep convergence guard (|t|>3e-4 -> flag), drop redundant
// final norm recompute. Slow path byte-identical to r4 (absmax 1.2e4, passed).

constexpr int BATCH  = 65536;
constexpr int VIEWS  = 4;
constexpr int JOINTS = 17;
constexpr int TOTAL  = BATCH * JOINTS;   // 1,114,112 = 4352 * 256

#define EPS32  5.9604645e-08f   /* slamch('E') = 2^-24 */
#define UNFL32 1.17549435e-38f  /* slamch('S') */

__device__ __forceinline__ float fsign(float a, float b) { return copysignf(a, b); }

// fast 1-ulp hardware ops (v_rcp_f32 / v_rsq_f32 / v_sqrt_f32) — fast path only
__device__ __forceinline__ float frcp(float x)  { return __builtin_amdgcn_rcpf(x); }
__device__ __forceinline__ float frsq(float x)  { return __builtin_amdgcn_rsqf(x); }
__device__ __forceinline__ float fsqrtf(float x){ return __builtin_amdgcn_sqrtf(x); }

// ===================== slow path (bit-identical to round 4) =====================

__device__ float snrm2_(const float* x, int n) {
    double s = 0.0;
    for (int i = 0; i < n; ++i) { double xi = (double)x[i]; s += xi * xi; }
    return (float)sqrt(s);
}

__device__ float slapy2_(float x, float y) {
    float xa = fabsf(x), ya = fabsf(y);
    float w = fmaxf(xa, ya), z = fminf(xa, ya);
    if (z == 0.0f) return w;
    float q = z / w;
    return w * __fsqrt_rn(1.0f + q * q);
}

__device__ float slarfg_(int n, float& alpha, float* x) {
    if (n <= 1) return 0.0f;
    float xnorm = snrm2_(x, n - 1);
    if (xnorm == 0.0f) return 0.0f;
    float beta = -fsign(slapy2_(alpha, xnorm), alpha);
    float tau  = (beta - alpha) / beta;
    float scal = 1.0f / (alpha - beta);
    for (int i = 0; i < n - 1; ++i) x[i] = scal * x[i];
    alpha = beta;
    return tau;
}

__device__ void slartg_(float f, float g, float& c, float& s, float& r) {
    if (g == 0.0f)      { c = 1.0f; s = 0.0f; r = f; }
    else if (f == 0.0f) { c = 0.0f; s = fsign(1.0f, g); r = fabsf(g); }
    else {
        float f1 = fabsf(f);
        float dd = __fsqrt_rn(f * f + g * g);
        c = f1 / dd;
        r = fsign(dd, f);
        s = g / r;
    }
}

__device__ void slas2_(float f, float g, float h, float& ssmin, float& ssmax) {
    float fa = fabsf(f), ga = fabsf(g), ha = fabsf(h);
    float fhmn = fminf(fa, ha), fhmx = fmaxf(fa, ha);
    if (fhmn == 0.0f) {
        ssmin = 0.0f;
        if (fhmx == 0.0f) ssmax = ga;
        else {
            float mn = fminf(fhmx, ga), mx = fmaxf(fhmx, ga);
            float q = mn / mx;
            ssmax = mx * __fsqrt_rn(1.0f + q * q);
        }
    } else {
        if (ga < fhmx) {
            float as_ = 1.0f + fhmn / fhmx;
            float at_ = (fhmx - fhmn) / fhmx;
            float q = ga / fhmx;
            float au = q * q;
            float cc = 2.0f / (__fsqrt_rn(as_ * as_ + au) + __fsqrt_rn(at_ * at_ + au));
            ssmin = fhmn * cc;
            ssmax = fhmx / cc;
        } else {
            float au = fhmx / ga;
            if (au == 0.0f) { ssmin = (fhmn * fhmx) / ga; ssmax = ga; }
            else {
                float as_ = 1.0f + fhmn / fhmx;
                float at_ = (fhmx - fhmn) / fhmx;
                float t1 = as_ * au, t2 = at_ * au;
                float cc = 1.0f / (__fsqrt_rn(1.0f + t1 * t1) + __fsqrt_rn(1.0f + t2 * t2));
                ssmin = (fhmn * cc) * au;
                ssmin = ssmin + ssmin;
                ssmax = ga / (cc + cc);
            }
        }
    }
}

__device__ void slasv2_(float f, float g, float h,
                        float& ssmin, float& ssmax,
                        float& snr, float& csr, float& snl, float& csl) {
    float ft = f, fa = fabsf(f), ht = h, ha = fabsf(h);
    int pmax = 1;
    bool swap = (ha > fa);
    if (swap) { pmax = 3; float t = ft; ft = ht; ht = t; t = fa; fa = ha; ha = t; }
    float gt = g, ga = fabsf(g);
    float clt = 0.0f, crt = 0.0f, slt = 0.0f, srt = 0.0f;
    if (ga == 0.0f) {
        ssmin = ha; ssmax = fa;
        clt = 1.0f; crt = 1.0f; slt = 0.0f; srt = 0.0f;
    } else {
        bool gasmal = true;
        if (ga > fa) {
            pmax = 2;
            if ((fa / ga) < EPS32) {
                gasmal = false;
                ssmax = ga;
                if (ha > 1.0f) ssmin = fa / (ga / ha);
                else           ssmin = (fa / ga) * ha;
                clt = 1.0f; slt = ht / gt;
                srt = 1.0f; crt = ft / gt;
            }
        }
        if (gasmal) {
            float dd = fa - ha;
            float l_ = (dd == fa) ? 1.0f : (dd / fa);
            float m_ = gt / ft;
            float t_ = 2.0f - l_;
            float mm = m_ * m_, tt = t_ * t_;
            float s_ = __fsqrt_rn(tt + mm);
            float r_ = (l_ == 0.0f) ? fabsf(m_) : __fsqrt_rn(l_ * l_ + mm);
            float a_ = 0.5f * (s_ + r_);
            ssmin = ha / a_;
            ssmax = fa * a_;
            if (mm == 0.0f) {
                if (l_ == 0.0f) t_ = fsign(2.0f, ft) * fsign(1.0f, gt);
                else            t_ = gt / fsign(dd, ft) + m_ / t_;
            } else {
                t_ = (m_ / (s_ + t_) + m_ / (r_ + l_)) * (1.0f + a_);
            }
            float ll = __fsqrt_rn(t_ * t_ + 4.0f);
            crt = 2.0f / ll;
            srt = t_ / ll;
            clt = (crt + srt * m_) / a_;
            slt = (ht / ft) * srt / a_;
        }
    }
    if (swap) { csl = srt; snl = crt; csr = slt; snr = clt; }
    else      { csl = clt; snl = slt; csr = crt; snr = srt; }
    float tsign = 0.0f;
    if (pmax == 1) tsign = fsign(1.0f, csr) * fsign(1.0f, csl) * fsign(1.0f, f);
    if (pmax == 2) tsign = fsign(1.0f, snr) * fsign(1.0f, csl) * fsign(1.0f, g);
    if (pmax == 3) tsign = fsign(1.0f, snr) * fsign(1.0f, snl) * fsign(1.0f, h);
    ssmax = fsign(ssmax, tsign);
    ssmin = fsign(ssmin, tsign * fsign(1.0f, f) * fsign(1.0f, h));
}

__device__ void sbdsqr4_(float* d, float* e, float VT[4][4]) {
    const float eps = EPS32, unfl = UNFL32;
    const float tol = 10.0f * eps;
    float thresh;
    {
        float sminoa = fabsf(d[0]);
        if (sminoa != 0.0f) {
            float mu = sminoa;
            for (int i = 1; i < 4; ++i) {
                mu = fabsf(d[i]) * (mu / (mu + fabsf(e[i - 1])));
                sminoa = fminf(sminoa, mu);
                if (sminoa == 0.0f) break;
            }
        }
        sminoa = sminoa / __fsqrt_rn(4.0f);
        thresh = fmaxf(tol * sminoa, 6.0f * (4.0f * (4.0f * unfl)));
    }
    int M = 4, oldll = -1000, oldm = -1000, idir = 0;
    float sminl = 0.0f;
    float rc[3], rs[3];
    for (int guard = 0; guard < 300 && M > 1; ++guard) {
        float smaxb = fabsf(d[M - 1]);
        int LLs = 0; bool defl = false, split = false;
        for (int lll = 1; lll <= M - 1; ++lll) {
            int ll = M - lll;
            float abse = fabsf(e[ll - 1]);
            float abss = fabsf(d[ll - 1]);
            if (abse <= thresh) {
                e[ll - 1] = 0.0f;
                if (ll == M - 1) { M = M - 1; defl = true; }
                else { LLs = ll; split = true; }
                break;
            }
            smaxb = fmaxf(fmaxf(smaxb, abss), abse);
        }
        if (defl) continue;
        int LL = (split ? LLs : 0) + 1;
        if (LL == M - 1) {
            float sigmn, sigmx, sinr, cosr, sinl, cosl;
            slasv2_(d[M - 2], e[M - 2], d[M - 1], sigmn, sigmx, sinr, cosr, sinl, cosl);
            d[M - 2] = sigmx; e[M - 2] = 0.0f; d[M - 1] = sigmn;
            for (int cc = 0; cc < 4; ++cc) {
                float st = cosr * VT[M - 2][cc] + sinr * VT[M - 1][cc];
                VT[M - 1][cc] = cosr * VT[M - 1][cc] - sinr * VT[M - 2][cc];
                VT[M - 2][cc] = st;
            }
            M -= 2;
            continue;
        }
        if (LL > oldm || M < oldll)
            idir = (fabsf(d[LL - 1]) >= fabsf(d[M - 1])) ? 1 : 2;
        bool cyc = false;
        if (idir == 1) {
            if (fabsf(e[M - 2]) <= tol * fabsf(d[M - 1])) { e[M - 2] = 0.0f; continue; }
            float mu = fabsf(d[LL - 1]); sminl = mu;
            for (int lll = LL; lll <= M - 1; ++lll) {
                if (fabsf(e[lll - 1]) <= tol * mu) { e[lll - 1] = 0.0f; cyc = true; break; }
                mu = fabsf(d[lll]) * (mu / (mu + fabsf(e[lll - 1])));
                sminl = fminf(sminl, mu);
            }
        } else {
            if (fabsf(e[LL - 1]) <= tol * fabsf(d[LL - 1])) { e[LL - 1] = 0.0f; continue; }
            float mu = fabsf(d[M - 1]); sminl = mu;
            for (int lll = M - 1; lll >= LL; --lll) {
                if (fabsf(e[lll - 1]) <= tol * mu) { e[lll - 1] = 0.0f; cyc = true; break; }
                mu = fabsf(d[lll - 1]) * (mu / (mu + fabsf(e[lll - 1])));
                sminl = fminf(sminl, mu);
            }
        }
        if (cyc) continue;
        oldll = LL; oldm = M;
        float shift = 0.0f;
        {
            float lhs = (4.0f * tol) * (sminl / smaxb);
            if (!(lhs <= fmaxf(eps, 0.01f * tol))) {
                float sll, rr2;
                if (idir == 1) { sll = fabsf(d[LL - 1]); slas2_(d[M - 2], e[M - 2], d[M - 1], shift, rr2); }
                else           { sll = fabsf(d[M - 1]); slas2_(d[LL - 1], e[LL - 1], d[LL], shift, rr2); }
                if (sll > 0.0f) {
                    float q = shift / sll;
                    if (q * q < eps) shift = 0.0f;
                }
            }
        }
        if (shift == 0.0f) {
            if (idir == 1) {
                float cs = 1.0f, oldcs = 1.0f, sn = 0.0f, oldsn = 0.0f, rr = 0.0f;
                for (int i = LL; i <= M - 1; ++i) {
                    float fv = d[i - 1] * cs;
                    slartg_(fv, e[i - 1], cs, sn, rr);
                    if (i > LL) e[i - 2] = oldsn * rr;
                    float fv2 = oldcs * rr;
                    float gv2 = d[i] * sn;
                    slartg_(fv2, gv2, oldcs, oldsn, d[i - 1]);
                    rc[i - LL] = cs; rs[i - LL] = sn;
                }
                float h = d[M - 1] * cs;
                d[M - 1] = h * oldcs;
                e[M - 2] = h * oldsn;
                for (int jj = 0; jj < M - LL; ++jj) {
                    float c = rc[jj], s = rs[jj];
                    if (c != 1.0f || s != 0.0f) {
                        int r0 = LL - 1 + jj;
                        for (int cc = 0; cc < 4; ++cc) {
                            float tmp = VT[r0 + 1][cc];
                            VT[r0 + 1][cc] = c * tmp - s * VT[r0][cc];
                            VT[r0][cc]     = s * tmp + c * VT[r0][cc];
                        }
                    }
                }
                if (fabsf(e[M - 2]) <= thresh) e[M - 2] = 0.0f;
            } else {
                float cs = 1.0f, oldcs = 1.0f, sn = 0.0f, oldsn = 0.0f, rr = 0.0f;
                for (int i = M; i >= LL + 1; --i) {
                    float fv = d[i - 1] * cs;
                    slartg_(fv, e[i - 2], cs, sn, rr);
                    if (i < M) e[i - 1] = oldsn * rr;
                    float fv2 = oldcs * rr;
                    float gv2 = d[i - 2] * sn;
                    slartg_(fv2, gv2, oldcs, oldsn, d[i - 1]);
                    rc[i - LL - 1] = oldcs; rs[i - LL - 1] = -oldsn;
                }
                float h = d[LL - 1] * cs;
                d[LL - 1] = h * oldcs;
                e[LL - 1] = h * oldsn;
                for (int jj = M - LL - 1; jj >= 0; --jj) {
                    float c = rc[jj], s = rs[jj];
                    if (c != 1.0f || s != 0.0f) {
                        int r0 = LL - 1 + jj;
                        for (int cc = 0; cc < 4; ++cc) {
                            float tmp = VT[r0 + 1][cc];
                            VT[r0 + 1][cc] = c * tmp - s * VT[r0][cc];
                            VT[r0][cc]     = s * tmp + c * VT[r0][cc];
                        }
                    }
                }
                if (fabsf(e[LL - 1]) <= thresh) e[LL - 1] = 0.0f;
            }
        } else {
            if (idir == 1) {
                float fv = (fabsf(d[LL - 1]) - shift) * (fsign(1.0f, d[LL - 1]) + shift / d[LL - 1]);
                float gv = e[LL - 1];
                float cosr, sinr, cosl, sinl, rr;
                for (int i = LL; i <= M - 1; ++i) {
                    slartg_(fv, gv, cosr, sinr, rr);
                    if (i > LL) e[i - 2] = rr;
                    fv = cosr * d[i - 1] + sinr * e[i - 1];
                    e[i - 1] = cosr * e[i - 1] - sinr * d[i - 1];
                    gv = sinr * d[i];
                    d[i] = cosr * d[i];
                    slartg_(fv, gv, cosl, sinl, rr);
                    d[i - 1] = rr;
                    fv = cosl * e[i - 1] + sinl * d[i];
                    d[i] = cosl * d[i] - sinl * e[i - 1];
                    if (i < M - 1) { gv = sinl * e[i]; e[i] = cosl * e[i]; }
                    rc[i - LL] = cosr; rs[i - LL] = sinr;
                }
                e[M - 2] = fv;
                for (int jj = 0; jj < M - LL; ++jj) {
                    float c = rc[jj], s = rs[jj];
                    if (c != 1.0f || s != 0.0f) {
                        int r0 = LL - 1 + jj;
                        for (int cc = 0; cc < 4; ++cc) {
                            float tmp = VT[r0 + 1][cc];
                            VT[r0 + 1][cc] = c * tmp - s * VT[r0][cc];
                            VT[r0][cc]     = s * tmp + c * VT[r0][cc];
                        }
                    }
                }
                if (fabsf(e[M - 2]) <= thresh) e[M - 2] = 0.0f;
            } else {
                float fv = (fabsf(d[M - 1]) - shift) * (fsign(1.0f, d[M - 1]) + shift / d[M - 1]);
                float gv = e[M - 2];
                float cosr, sinr, cosl, sinl, rr;
                for (int i = M; i >= LL + 1; --i) {
                    slartg_(fv, gv, cosr, sinr, rr);
                    if (i < M) e[i - 1] = rr;
                    fv = cosr * d[i - 1] + sinr * e[i - 2];
                    e[i - 2] = cosr * e[i - 2] - sinr * d[i - 1];
                    gv = sinr * d[i - 2];
                    d[i - 2] = cosr * d[i - 2];
                    slartg_(fv, gv, cosl, sinl, rr);
                    d[i - 1] = rr;
                    fv = cosl * e[i - 2] + sinl * d[i - 2];
                    d[i - 2] = cosl * d[i - 2] - sinl * e[i - 2];
                    if (i > LL + 1) { gv = sinl * e[i - 3]; e[i - 3] = cosl * e[i - 3]; }
                    rc[i - LL - 1] = cosl; rs[i - LL - 1] = -sinl;
                }
                e[LL - 1] = fv;
                if (fabsf(e[LL - 1]) <= thresh) e[LL - 1] = 0.0f;
                for (int jj = M - LL - 1; jj >= 0; --jj) {
                    float c = rc[jj], s = rs[jj];
                    if (c != 1.0f || s != 0.0f) {
                        int r0 = LL - 1 + jj;
                        for (int cc = 0; cc < 4; ++cc) {
                            float tmp = VT[r0 + 1][cc];
                            VT[r0 + 1][cc] = c * tmp - s * VT[r0][cc];
                            VT[r0][cc]     = s * tmp + c * VT[r0][cc];
                        }
                    }
                }
            }
        }
    }
    for (int i = 0; i < 4; ++i) {
        if (d[i] < 0.0f) {
            d[i] = -d[i];
            for (int cc = 0; cc < 4; ++cc) VT[i][cc] = -VT[i][cc];
        }
    }
    for (int i = 1; i <= 3; ++i) {
        int isub = 0; float smn = d[0];
        for (int jj = 1; jj <= 4 - i; ++jj)
            if (d[jj] <= smn) { isub = jj; smn = d[jj]; }
        int tgt = 4 - i;
        if (isub != tgt) {
            d[isub] = d[tgt]; d[tgt] = smn;
            for (int cc = 0; cc < 4; ++cc) {
                float t = VT[isub][cc]; VT[isub][cc] = VT[tgt][cc]; VT[tgt][cc] = t;
            }
        }
    }
}

// Build A (8x4) in f32 with numpy's exact op order; column-major Acm[col][row].
__device__ __forceinline__ void build_A(const float* __restrict__ points,
                                        const float* __restrict__ confs,
                                        const float* __restrict__ proj,
                                        int b, int j, float Acm[4][8]) {
    #pragma unroll
    for (int v = 0; v < VIEWS; ++v) {
        int bv = b * VIEWS + v;
        const float4* Pq = (const float4*)(proj + (size_t)bv * 12);
        float4 P0 = Pq[0];
        float4 P1 = Pq[1];
        float4 P2 = Pq[2];
        float2 pt = *(const float2*)(points + ((size_t)bv * JOINTS + j) * 2);
        float  cf = confs[(size_t)bv * JOINTS + j];
        float p2[4] = {P2.x, P2.y, P2.z, P2.w};
        float p0[4] = {P0.x, P0.y, P0.z, P0.w};
        float p1[4] = {P1.x, P1.y, P1.z, P1.w};
        #pragma unroll
        for (int cc = 0; cc < 4; ++cc) {
            float r0 = (p2[cc] * pt.x) - p0[cc];
            float r1 = (p2[cc] * pt.y) - p1[cc];
            Acm[cc][2 * v + 0] = r0 * cf;
            Acm[cc][2 * v + 1] = r1 * cf;
        }
    }
}

__global__ __launch_bounds__(256) void triangulate_kernel(
    const float* __restrict__ points,   // (B,V,J,2)
    const float* __restrict__ confs,    // (B,V,J)
    const float* __restrict__ proj,     // (B,V,3,4)
    float* __restrict__ out)            // (B,J,3)
{
    int tid = blockIdx.x * blockDim.x + threadIdx.x;
    if (tid >= TOTAL) return;
    int b = tid / JOINTS;
    int j = tid - b * JOINTS;

    // ================= FAST PATH: f32 one-sided Jacobi =================
    float Acm[4][8];
    build_A(points, confs, proj, b, j, Acm);

    float V[4][4] = {{1,0,0,0},{0,1,0,0},{0,0,1,0},{0,0,0,1}};

    // column norms, maintained incrementally across rotations
    float nrm[4];
    #pragma unroll
    for (int c = 0; c < 4; ++c) {
        float s = 0.0f;
        #pragma unroll
        for (int i = 0; i < 8; ++i) s = fmaf(Acm[c][i], Acm[c][i], s);
        nrm[c] = s;
    }

    bool badconv = false;
    for (int sweep = 0; sweep < 5; ++sweep) {
        bool last = (sweep == 4);
        bool rot = false;
        #pragma unroll
        for (int p = 0; p < 3; ++p) {
            #pragma unroll
            for (int q = p + 1; q < 4; ++q) {
                float alpha = nrm[p], beta = nrm[q];
                float gamma = 0.0f;
                #pragma unroll
                for (int i = 0; i < 8; ++i)
                    gamma = fmaf(Acm[p][i], Acm[q][i], gamma);
                if (gamma * gamma > 1e-14f * (alpha * beta)) {
                    rot = true;
                    float zeta = 0.5f * (beta - alpha) * frcp(gamma);
                    float t  = fsign(frcp(fabsf(zeta) +
                                          fsqrtf(fmaf(zeta, zeta, 1.0f))), zeta);
                    if (last && fabsf(t) > 3e-4f) badconv = true;
                    float ci = frsq(fmaf(t, t, 1.0f));
                    float si = ci * t;
                    #pragma unroll
                    for (int i = 0; i < 8; ++i) {
                        float ap = Acm[p][i], aq = Acm[q][i];
                        Acm[p][i] = fmaf(ci, ap, -si * aq);
                        Acm[q][i] = fmaf(si, ap,  ci * aq);
                    }
                    #pragma unroll
                    for (int i = 0; i < 4; ++i) {
                        float vp = V[i][p], vq = V[i][q];
                        V[i][p] = fmaf(ci, vp, -si * vq);
                        V[i][q] = fmaf(si, vp,  ci * vq);
                    }
                    nrm[p] = fmaf(-t, gamma, alpha);
                    nrm[q] = fmaf( t, gamma, beta);
                }
            }
        }
        if (!__any((int)rot)) break;
    }

    // smallest column norm -> sigma_min's right singular vector
    int idx = 0; float nm = nrm[0];
    if (nrm[1] < nm) { nm = nrm[1]; idx = 1; }
    if (nrm[2] < nm) { nm = nrm[2]; idx = 2; }
    if (nrm[3] < nm) { nm = nrm[3]; idx = 3; }

    // sort singular values ascending (5-compare network)
    float s0 = fsqrtf(nrm[0]), s1 = fsqrtf(nrm[1]);
    float s2 = fsqrtf(nrm[2]), s3 = fsqrtf(nrm[3]);
    { float t;
      if (s0 > s1) { t = s0; s0 = s1; s1 = t; }
      if (s2 > s3) { t = s2; s2 = s3; s3 = t; }
      if (s0 > s2) { t = s0; s0 = s2; s2 = t; }
      if (s1 > s3) { t = s1; s1 = s3; s3 = t; }
      if (s1 > s2) { t = s1; s1 = s2; s2 = t; }
    }
    float gap = s1 - s0;   // gap==0 -> frcp(0)=inf -> est=inf -> flagged

    float hw  = V[3][idx];
    float inv = frcp(hw);
    float ox = V[0][idx] * inv;
    float oy = V[1][idx] * inv;
    float oz = V[2][idx] * inv;

    float osq = fmaf(ox, ox, fmaf(oy, oy, oz * oz));
    float est = EPS32 * (s3 * frcp(gap)) * (1.0f + osq);
    // cutoff 1000: model |fast-ref| <~ 6*est = 6e3 << threshold 1.9e4;
    // !(x<=) also catches NaN/inf. badconv catches clustered-sigma stragglers.
    bool flag = !(est <= 1000.0f) || badconv;

    // ================= SLOW PATH: faithful sgesdd-f32 emulation =================
    if (flag) {
        build_A(points, confs, proj, b, j, Acm);

        // sgeqr2 (8x4)
        for (int jc = 0; jc < 4; ++jc) {
            float alpha = Acm[jc][jc];
            float tau = slarfg_(8 - jc, alpha, &Acm[jc][jc + 1]);
            if (tau != 0.0f) {
                for (int c = jc + 1; c < 4; ++c) {
                    float w = Acm[c][jc];
                    for (int r = jc + 1; r < 8; ++r) w = w + Acm[jc][r] * Acm[c][r];
                    float temp = -tau * w;
                    Acm[c][jc] = Acm[c][jc] + temp;
                    for (int r = jc + 1; r < 8; ++r) Acm[c][r] = Acm[c][r] + Acm[jc][r] * temp;
                }
            }
            Acm[jc][jc] = alpha;
        }

        float Rg[4][4];
        #pragma unroll
        for (int c = 0; c < 4; ++c)
            #pragma unroll
            for (int r = 0; r < 4; ++r)
                Rg[c][r] = (r <= c) ? Acm[c][r] : 0.0f;

        // sgebd2 (4x4)
        float d_[4], e_[4], taup[4];
        for (int i = 0; i < 4; ++i) {
            float alpha = Rg[i][i];
            float tau = slarfg_(4 - i, alpha, &Rg[i][i + 1]);
            d_[i] = alpha;
            if (tau != 0.0f) {
                for (int c = i + 1; c < 4; ++c) {
                    float w = Rg[c][i];
                    for (int r = i + 1; r < 4; ++r) w = w + Rg[i][r] * Rg[c][r];
                    float temp = -tau * w;
                    Rg[c][i] = Rg[c][i] + temp;
                    for (int r = i + 1; r < 4; ++r) Rg[c][r] = Rg[c][r] + Rg[i][r] * temp;
                }
            }
            if (i < 3) {
                float alpha2 = Rg[i + 1][i];
                float xb[2]; int nt = 2 - i;
                for (int t = 0; t < nt && t < 2; ++t) xb[t] = Rg[i + 2 + t][i];
                float tau2 = slarfg_(3 - i, alpha2, xb);
                e_[i] = alpha2;
                for (int t = 0; t < nt && t < 2; ++t) Rg[i + 2 + t][i] = xb[t];
                taup[i] = tau2;
                if (tau2 != 0.0f) {
                    for (int r = i + 1; r < 4; ++r) {
                        float w = Rg[i + 1][r];
                        for (int c = i + 2; c < 4; ++c) w = w + Rg[c][i] * Rg[c][r];
                        float ntau = -tau2;
                        Rg[i + 1][r] = Rg[i + 1][r] + w * ntau;
                        for (int c = i + 2; c < 4; ++c) {
                            float tc = ntau * Rg[c][i];
                            Rg[c][r] = Rg[c][r] + w * tc;
                        }
                    }
                }
            } else taup[i] = 0.0f;
        }

        float VT[4][4] = {{1,0,0,0},{0,1,0,0},{0,0,1,0},{0,0,0,1}};
        sbdsqr4_(d_, e_, VT);

        // sormbr('P','R','T') backward
        for (int ii = 2; ii >= 0; --ii) {
            float tau = taup[ii];
            if (tau == 0.0f) continue;
            for (int r = 0; r < 4; ++r) {
                float w = VT[r][ii + 1];
                for (int c = ii + 2; c < 4; ++c) w = w + VT[r][c] * Rg[c][ii];
                float ntau = -tau;
                VT[r][ii + 1] = VT[r][ii + 1] + w * ntau;
                for (int c = ii + 2; c < 4; ++c) {
                    float tc = ntau * Rg[c][ii];
                    VT[r][c] = VT[r][c] + w * tc;
                }
            }
        }

        float w3 = VT[3][3];
        ox = VT[3][0] / w3;
        oy = VT[3][1] / w3;
        oz = VT[3][2] / w3;
    }

    float* o = out + (size_t)tid * 3;
    o[0] = ox;
    o[1] = oy;
    o[2] = oz;
}

extern "C" void kernel_launch(void* const* d_in, const int* in_sizes, int n_in,
                              void* d_out, int out_size, void* d_ws, size_t ws_size,
                              hipStream_t stream) {
    const float* points = (const float*)d_in[0];
    const float* confs  = (const float*)d_in[1];
    const float* proj   = (const float*)d_in[2];
    float* out = (float*)d_out;

    dim3 block(256);
    dim3 grid((TOTAL + 255) / 256);   // 4352
    triangulate_kernel<<<grid, block, 0, stream>>>(points, confs, proj, out);
}